// Round 10
// baseline (201.157 us; speedup 1.0000x reference)
//
#include <hip/hip_runtime.h>
#include <hip/hip_bf16.h>

typedef __bf16 bf16;
typedef __bf16 bf16x8 __attribute__((ext_vector_type(8)));
typedef __bf16 bf16x4v __attribute__((ext_vector_type(4)));
typedef float f32x4 __attribute__((ext_vector_type(4)));
typedef float f32x16 __attribute__((ext_vector_type(16)));
typedef float float4v __attribute__((ext_vector_type(4)));
typedef unsigned int uint32x4 __attribute__((ext_vector_type(4)));

#define MFMA16(a, b, c) __builtin_amdgcn_mfma_f32_16x16x32_bf16(a, b, c, 0, 0, 0)
#define MFMA32(a, b, c) __builtin_amdgcn_mfma_f32_32x32x16_bf16(a, b, c, 0, 0, 0)

// q pre-scale: 1/sqrt(64) * log2(e)  (softmax runs in exp2 domain)
#define SCALE_Q 0.1803368801111f

__device__ __forceinline__ void async_load16(const bf16* g, bf16* l) {
    __builtin_amdgcn_global_load_lds(
        (const __attribute__((address_space(1))) void*)g,
        (__attribute__((address_space(3))) void*)l,
        16, 0, 0);
}

__device__ __forceinline__ unsigned int pack2bf(float a, float b) {
    bf16 x = (bf16)a, y = (bf16)b;
    unsigned short ux = __builtin_bit_cast(unsigned short, x);
    unsigned short uy = __builtin_bit_cast(unsigned short, y);
    return (unsigned int)ux | ((unsigned int)uy << 16);
}

// ---------------- fused preprocessing: cast x (+ new_memory copy) + W transposes ----------------
__global__ void k_pre(const float* __restrict__ x, const float* __restrict__ W_attn,
                      const float* __restrict__ W_proj,
                      bf16* __restrict__ xb, float* __restrict__ out_mem,
                      bf16* __restrict__ WaT, bf16* __restrict__ WpT) {
    __shared__ float tile[32][33];
    int bid = blockIdx.x;
    if (bid < 8192) {
        int i = bid * 256 + threadIdx.x;     // float4 index, 2097152 total
        float4v v = ((const float4v*)x)[i];
        bf16x4v o;
        o.x = (bf16)v.x; o.y = (bf16)v.y; o.z = (bf16)v.z; o.w = (bf16)v.w;
        ((bf16x4v*)xb)[i] = o;
        int rem = i & 524287;
        if (rem >= 393216) {
            int b = i >> 19;
            ((float4v*)out_mem)[(size_t)b * 131072 + (rem - 393216)] = v;
        }
        return;
    }
    const float* W;  bf16* WT;  int R, Cc, bx, by;
    if (bid < 8192 + 3072) {
        int idx = bid - 8192;
        W = W_attn; WT = WaT; R = 1024; Cc = 3072; bx = idx % 96; by = idx / 96;
    } else {
        int idx = bid - 11264;
        W = W_proj; WT = WpT; R = 1024; Cc = 1024; bx = idx & 31; by = idx >> 5;
    }
    int r0 = by * 32, c0 = bx * 32;
    int tx = threadIdx.x & 31, ty = threadIdx.x >> 5;
#pragma unroll
    for (int i = 0; i < 32; i += 8)
        tile[ty + i][tx] = W[(size_t)(r0 + ty + i) * Cc + c0 + tx];
    __syncthreads();
#pragma unroll
    for (int i = 0; i < 32; i += 8)
        WT[(size_t)(c0 + ty + i) * R + r0 + tx] = (bf16)tile[tx][ty + i];
}

// ======================= phase-pipelined 128x256 GEMM template =======================
// BM=128, BN=256, BK=64, 512 thr = 8 waves (1M x 8N). Per wave: 8 m-frags x 2 n-frags.
// LDS: As[2][128x64] 32KB + Bs[2][256x64] 64KB = 96KB (1 block/CU).
// 2 phases per K-tile, 16 MFMA per phase; counted vmcnt(4) at tile boundary only.
// Slot-involution swizzle (conflict-free, r9-proven): LDS[row][slot] = G[row][slot^(row&7)].
// Stage schedule: tile t P0 stages A(t+1) (2 loads, slot freed at t-1 boundary);
// P1 stages B(t+2) (4 loads, B(t) fully read in P0). Publish: own-vmcnt before barrier.

#define STG_A(db, k0) { \
    async_load16(Asrc + (k0), &As[(db)][tid8]); \
    async_load16(Asrc + (size_t)64 * 1024 + (k0), &As[(db)][4096 + tid8]); }
#define STG_B(db, k0) { \
    async_load16(Bsrc + (k0), &Bs[(db)][tid8]); \
    async_load16(Bsrc + (size_t)64 * 1024 + (k0), &Bs[(db)][4096 + tid8]); \
    async_load16(Bsrc + (size_t)128 * 1024 + (k0), &Bs[(db)][8192 + tid8]); \
    async_load16(Bsrc + (size_t)192 * 1024 + (k0), &Bs[(db)][12288 + tid8]); }

#define GEMM_PIPE_BODY                                                                   \
    STG_A(0, 0)                                                                          \
    STG_B(0, 0)                                                                          \
    STG_B(1, 64)                                                                         \
    asm volatile("s_waitcnt vmcnt(4)" ::: "memory");                                     \
    __builtin_amdgcn_sched_barrier(0);                                                   \
    __builtin_amdgcn_s_barrier();                                                        \
    __builtin_amdgcn_sched_barrier(0);                                                   \
    for (int t = 0; t < 16; ++t) {                                                       \
        int db = t & 1;                                                                  \
        bf16x8 bfr[2][2], af[4][2];                                                      \
        /* ---- phase 0: read B(all)+A(m0-3); stage A(t+1); MFMA m0-3 ---- */            \
        _Pragma("unroll")                                                                \
        for (int nf = 0; nf < 2; ++nf) {                                                 \
            bfr[nf][0] = *(const bf16x8*)&Bs[db][w * 2048 + nf * 1024 + lrow64 + slot0]; \
            bfr[nf][1] = *(const bf16x8*)&Bs[db][w * 2048 + nf * 1024 + lrow64 + slot1]; \
        }                                                                                \
        _Pragma("unroll")                                                                \
        for (int mi = 0; mi < 4; ++mi) {                                                 \
            af[mi][0] = *(const bf16x8*)&As[db][mi * 1024 + lrow64 + slot0];             \
            af[mi][1] = *(const bf16x8*)&As[db][mi * 1024 + lrow64 + slot1];             \
        }                                                                                \
        if (t + 1 < 16) STG_A(db ^ 1, (t + 1) * 64)                                      \
        __builtin_amdgcn_sched_barrier(0);                                               \
        __builtin_amdgcn_s_barrier();                                                    \
        asm volatile("s_waitcnt lgkmcnt(0)" ::: "memory");                               \
        __builtin_amdgcn_sched_barrier(0);                                               \
        __builtin_amdgcn_s_setprio(1);                                                   \
        _Pragma("unroll")                                                                \
        for (int mi = 0; mi < 4; ++mi)                                                   \
            _Pragma("unroll")                                                            \
            for (int nf = 0; nf < 2; ++nf) {                                             \
                acc[mi][nf] = MFMA16(af[mi][0], bfr[nf][0], acc[mi][nf]);                \
                acc[mi][nf] = MFMA16(af[mi][1], bfr[nf][1], acc[mi][nf]);                \
            }                                                                            \
        __builtin_amdgcn_s_setprio(0);                                                   \
        __builtin_amdgcn_sched_barrier(0);                                               \
        __builtin_amdgcn_s_barrier();                                                    \
        __builtin_amdgcn_sched_barrier(0);                                               \
        /* ---- phase 1: read A(m4-7); stage B(t+2); MFMA m4-7 ---- */                   \
        _Pragma("unroll")                                                                \
        for (int mi = 0; mi < 4; ++mi) {                                                 \
            af[mi][0] = *(const bf16x8*)&As[db][(4 + mi) * 1024 + lrow64 + slot0];       \
            af[mi][1] = *(const bf16x8*)&As[db][(4 + mi) * 1024 + lrow64 + slot1];       \
        }                                                                                \
        if (t + 2 < 16) STG_B(db, (t + 2) * 64)                                          \
        __builtin_amdgcn_sched_barrier(0);                                               \
        __builtin_amdgcn_s_barrier();                                                    \
        asm volatile("s_waitcnt lgkmcnt(0)" ::: "memory");                               \
        __builtin_amdgcn_sched_barrier(0);                                               \
        __builtin_amdgcn_s_setprio(1);                                                   \
        _Pragma("unroll")                                                                \
        for (int mi = 0; mi < 4; ++mi)                                                   \
            _Pragma("unroll")                                                            \
            for (int nf = 0; nf < 2; ++nf) {                                             \
                acc[4 + mi][nf] = MFMA16(af[mi][0], bfr[nf][0], acc[4 + mi][nf]);        \
                acc[4 + mi][nf] = MFMA16(af[mi][1], bfr[nf][1], acc[4 + mi][nf]);        \
            }                                                                            \
        __builtin_amdgcn_s_setprio(0);                                                   \
        __builtin_amdgcn_sched_barrier(0);                                               \
        if (t + 2 < 16) { asm volatile("s_waitcnt vmcnt(4)" ::: "memory"); }             \
        else            { asm volatile("s_waitcnt vmcnt(0)" ::: "memory"); }             \
        __builtin_amdgcn_sched_barrier(0);                                               \
        __builtin_amdgcn_s_barrier();                                                    \
        __builtin_amdgcn_sched_barrier(0);                                               \
    }

// ---------------- QKV GEMM (M=8192, N=3072): grid 768 = 3 exact CU rounds ----------------
__global__ __launch_bounds__(512, 2) void k_gemm_qkv(
    const bf16* __restrict__ A, const bf16* __restrict__ BT,
    const float* __restrict__ bias,
    bf16* __restrict__ qo, bf16* __restrict__ ko, bf16* __restrict__ vo) {
    __shared__ __align__(16) bf16 As[2][8192];
    __shared__ __align__(16) bf16 Bs[2][16384];
    int orig = blockIdx.x;                       // 768 = 8 * 96, bijective XCD chunking
    int wg = (orig & 7) * 96 + (orig >> 3);
    int row0 = (wg / 12) * 128;
    int col0 = (wg % 12) * 256;
    int tid = threadIdx.x;
    int lane = tid & 63, w = tid >> 6;
    int lrow = lane & 15, lks = lane >> 4;
    int lrow64 = lrow * 64;
    int slot0 = (lks ^ (lane & 7)) * 8;
    int slot1 = ((lks + 4) ^ (lane & 7)) * 8;
    int arow = tid >> 3;
    int sw = ((tid & 7) ^ (arow & 7)) * 8;
    int tid8 = tid * 8;
    const bf16* Asrc = A + (size_t)(row0 + arow) * 1024 + sw;
    const bf16* Bsrc = BT + (size_t)(col0 + arow) * 1024 + sw;
    f32x4 acc[8][2] = {};

    GEMM_PIPE_BODY

    // epilogue: packed scatter (branch uniform per block: 256-col tile within one region)
    int tcolb = col0 + w * 32 + lrow;
#pragma unroll
    for (int nf = 0; nf < 2; ++nf) {
        int cg = tcolb + nf * 16;
        float bi = bias[cg];
#pragma unroll
        for (int mf = 0; mf < 8; ++mf)
#pragma unroll
            for (int j = 0; j < 4; ++j) {
                int rg = row0 + mf * 16 + lks * 4 + j;
                float val = acc[mf][nf][j] + bi;
                int b = rg >> 11, tt = rg & 2047;
                if (cg < 1024) {
                    int h = cg >> 6, d = cg & 63;
                    size_t base = (size_t)(b * 16 + h) * 131072;
                    size_t idx = base + (size_t)((((tt >> 5) * 4 + (d >> 4)) * 64 + ((d >> 3) & 1) * 32 + (tt & 31)) * 8 + (d & 7));
                    qo[idx] = (bf16)(val * SCALE_Q);
                } else if (cg < 2048) {
                    int c2 = cg - 1024;
                    int h = c2 >> 6, d = c2 & 63;
                    size_t base = (size_t)(b * 16 + h) * 131072;
                    size_t idx = base + (size_t)((((tt >> 5) * 4 + (d >> 4)) * 64 + ((d >> 3) & 1) * 32 + (tt & 31)) * 8 + (d & 7));
                    ko[idx] = (bf16)val;
                } else {
                    int c2 = cg - 2048;
                    int h = c2 >> 6, d = c2 & 63;
                    size_t base = (size_t)(b * 16 + h) * 131072;
                    size_t idx = base + (size_t)(((((tt >> 6) * 4 + ((tt >> 4) & 3)) * 2 + (d >> 5)) * 64 + ((tt >> 3) & 1) * 32 + (d & 31)) * 8 + (tt & 7));
                    vo[idx] = (bf16)val;
                }
            }
    }
}

// ---------------- proj GEMM (M=8192, N=1024): grid 256 = 1 exact CU round ----------------
__global__ __launch_bounds__(512, 2) void k_gemm_proj(
    const bf16* __restrict__ A, const bf16* __restrict__ BT,
    const float* __restrict__ bias, float* __restrict__ out) {
    __shared__ __align__(16) bf16 As[2][8192];
    __shared__ __align__(16) bf16 Bs[2][16384];
    int orig = blockIdx.x;                       // 256 = 8 * 32
    int wg = (orig & 7) * 32 + (orig >> 3);
    int row0 = (wg >> 2) * 128;
    int col0 = (wg & 3) * 256;
    int tid = threadIdx.x;
    int lane = tid & 63, w = tid >> 6;
    int lrow = lane & 15, lks = lane >> 4;
    int lrow64 = lrow * 64;
    int slot0 = (lks ^ (lane & 7)) * 8;
    int slot1 = ((lks + 4) ^ (lane & 7)) * 8;
    int arow = tid >> 3;
    int sw = ((tid & 7) ^ (arow & 7)) * 8;
    int tid8 = tid * 8;
    const bf16* Asrc = A + (size_t)(row0 + arow) * 1024 + sw;
    const bf16* Bsrc = BT + (size_t)(col0 + arow) * 1024 + sw;
    f32x4 acc[8][2] = {};

    GEMM_PIPE_BODY

    int tcolb = col0 + w * 32 + lrow;
#pragma unroll
    for (int nf = 0; nf < 2; ++nf) {
        int cg = tcolb + nf * 16;
        float bi = bias[cg];
#pragma unroll
        for (int mf = 0; mf < 8; ++mf)
#pragma unroll
            for (int j = 0; j < 4; ++j) {
                int rg = row0 + mf * 16 + lks * 4 + j;
                out[(size_t)rg * 1024 + cg] = acc[mf][nf][j] + bi;
            }
    }
}

// ---------------- flash attention (causal), LDS-shared K/V tiles (r7, unchanged) ----------------
__global__ __launch_bounds__(256, 2) void k_attn(
    const bf16* __restrict__ qp, const bf16* __restrict__ kp,
    const bf16* __restrict__ vp, bf16* __restrict__ y) {
    __shared__ __align__(16) bf16 Ks[2][4096];
    __shared__ __align__(16) bf16 Vs[2][4096];
    int bh = blockIdx.y;
    int b = bh >> 4;
    int lane = threadIdx.x & 63, w = threadIdx.x >> 6;
    int tl = lane & 31, hi = lane >> 5;
    int lane8 = lane * 8;
    const bf16* Qb = qp + (size_t)bh * 131072;
    const bf16* Kb = kp + (size_t)bh * 131072;
    const bf16* Vb = vp + (size_t)bh * 131072;

    for (int qpass = 0; qpass < 2; ++qpass) {
        int qt0 = (qpass ? 15 - (int)blockIdx.x : (int)blockIdx.x) * 128;
        int trow0 = qt0 + w * 32;
        int t_g = trow0 + tl;

        bf16x8 qf[4];
        int qs = (trow0 >> 5) * 4;
#pragma unroll
        for (int kc = 0; kc < 4; ++kc)
            qf[kc] = *(const bf16x8*)&Qb[(qs + kc) * 512 + lane8];

        f32x16 o[2] = {};
        float m = -1e30f, l = 0.f;
        int ntb = (qt0 >> 6) + 2;
        int cur = 0;

#pragma unroll
        for (int i = 0; i < 2; ++i) {
            int u = 2 * w + i;
            async_load16(Kb + (size_t)u * 512 + lane8, &Ks[0][u * 512]);
            async_load16(Vb + (size_t)u * 512 + lane8, &Vs[0][u * 512]);
        }
        __syncthreads();

        for (int ti = 0; ti < ntb; ++ti) {
            int s0 = ti * 64;
            if (ti + 1 < ntb) {
#pragma unroll
                for (int i = 0; i < 2; ++i) {
                    int u = 2 * w + i;
                    async_load16(Kb + (size_t)((ti + 1) * 8 + u) * 512 + lane8, &Ks[cur ^ 1][u * 512]);
                    async_load16(Vb + (size_t)((ti + 1) * 8 + u) * 512 + lane8, &Vs[cur ^ 1][u * 512]);
                }
            }
            if (s0 < trow0 + 32) {
                f32x16 accs[2] = {};
                __builtin_amdgcn_s_setprio(1);
#pragma unroll
                for (int st = 0; st < 2; ++st)
#pragma unroll
                    for (int kc = 0; kc < 4; ++kc) {
                        bf16x8 kf = *(const bf16x8*)&Ks[cur][(st * 4 + kc) * 512 + lane8];
                        accs[st] = MFMA32(kf, qf[kc], accs[st]);
                    }
                __builtin_amdgcn_s_setprio(0);

                if (s0 + 63 > trow0) {
#pragma unroll
                    for (int st = 0; st < 2; ++st)
#pragma unroll
                        for (int r = 0; r < 16; ++r) {
                            int s = s0 + st * 32 + (r & 3) + 8 * (r >> 2) + 4 * hi;
                            if (s > t_g) accs[st][r] = -1e30f;
                        }
                }
                float pmax = -1e30f;
#pragma unroll
                for (int st = 0; st < 2; ++st)
#pragma unroll
                    for (int r = 0; r < 16; ++r)
                        pmax = fmaxf(pmax, accs[st][r]);
                pmax = fmaxf(pmax, __shfl_xor(pmax, 32));
                if (!__all(pmax <= m + 8.0f)) {
                    float mn = fmaxf(m, pmax);
                    float corr = __builtin_amdgcn_exp2f(m - mn);
                    m = mn;
                    l *= corr;
#pragma unroll
                    for (int dt = 0; dt < 2; ++dt)
#pragma unroll
                        for (int r = 0; r < 16; ++r)
                            o[dt][r] *= corr;
                }
                float ls = 0.f;
#pragma unroll
                for (int st = 0; st < 2; ++st)
#pragma unroll
                    for (int r = 0; r < 16; ++r) {
                        float p = __builtin_amdgcn_exp2f(accs[st][r] - m);
                        accs[st][r] = p;
                        ls += p;
                    }
                ls += __shfl_xor(ls, 32);
                l += ls;

                unsigned int pk[16];
#pragma unroll
                for (int st = 0; st < 2; ++st)
#pragma unroll
                    for (int q = 0; q < 8; ++q)
                        pk[st * 8 + q] = pack2bf(accs[st][2 * q], accs[st][2 * q + 1]);
                unsigned int rv[8];
#pragma unroll
                for (int st = 0; st < 2; ++st)
#pragma unroll
                    for (int i = 0; i < 4; ++i) {
                        int base = st * 8 + (i < 2 ? i : i + 2);
                        unsigned int send = hi ? pk[base] : pk[base + 2];
                        rv[st * 4 + i] = __shfl_xor(send, 32);
                    }
                __builtin_amdgcn_s_setprio(1);
#pragma unroll
                for (int c = 0; c < 4; ++c) {
                    const int st = c >> 1, c2 = c & 1;
                    uint32x4 pw;
                    pw.x = hi ? rv[st * 4 + 2 * c2]     : pk[st * 8 + 4 * c2];
                    pw.y = hi ? rv[st * 4 + 2 * c2 + 1] : pk[st * 8 + 4 * c2 + 1];
                    pw.z = hi ? pk[st * 8 + 4 * c2 + 2] : rv[st * 4 + 2 * c2];
                    pw.w = hi ? pk[st * 8 + 4 * c2 + 3] : rv[st * 4 + 2 * c2 + 1];
                    bf16x8 pf = __builtin_bit_cast(bf16x8, pw);
#pragma unroll
                    for (int dt = 0; dt < 2; ++dt) {
                        bf16x8 vf = *(const bf16x8*)&Vs[cur][(c * 2 + dt) * 512 + lane8];
                        o[dt] = MFMA32(vf, pf, o[dt]);
                    }
                }
                __builtin_amdgcn_s_setprio(0);
            }
            __syncthreads();
            cur ^= 1;
        }

        int hcol = (bh & 15) * 64;
        float inv = 1.0f / l;
        bf16* yr = y + (size_t)(b * 2048 + t_g) * 1024 + hcol;
#pragma unroll
        for (int dt = 0; dt < 2; ++dt)
#pragma unroll
            for (int rq = 0; rq < 4; ++rq) {
                bf16x4v ov;
#pragma unroll
                for (int ri = 0; ri < 4; ++ri)
                    ov[ri] = (bf16)(o[dt][rq * 4 + ri] * inv);
                *(bf16x4v*)&yr[dt * 32 + rq * 8 + hi * 4] = ov;
            }
    }
}

extern "C" void kernel_launch(void* const* d_in, const int* in_sizes, int n_in,
                              void* d_out, int out_size, void* d_ws, size_t ws_size,
                              hipStream_t stream) {
    const float* x = (const float*)d_in[0];
    const float* W_attn = (const float*)d_in[1];
    const float* b_attn = (const float*)d_in[2];
    const float* W_proj = (const float*)d_in[3];
    const float* b_proj = (const float*)d_in[4];
    float* out = (float*)d_out;
    float* out_mem = out + (size_t)8388608;

    char* ws = (char*)d_ws;
    bf16* xb  = (bf16*)(ws);                         // 16MB  [8192][1024]
    bf16* WaT = (bf16*)(ws + ((size_t)16 << 20));    // 6MB   [3072][1024]
    bf16* WpT = (bf16*)(ws + ((size_t)22 << 20));    // 2MB   [1024][1024]
    bf16* q   = (bf16*)(ws + ((size_t)24 << 20));    // 16MB  packed frags
    bf16* k   = (bf16*)(ws + ((size_t)40 << 20));    // 16MB  packed frags
    bf16* vT  = (bf16*)(ws + ((size_t)56 << 20));    // 16MB  packed frags
    bf16* y   = (bf16*)(ws + ((size_t)72 << 20));    // 16MB  [8192][1024]

    k_pre<<<12288, 256, 0, stream>>>(x, W_attn, W_proj, xb, out_mem, WaT, WpT);
    k_gemm_qkv<<<768, 512, 0, stream>>>(xb, WaT, b_attn, q, k, vT);
    k_attn<<<dim3(8, 64), 256, 0, stream>>>(q, k, vT, y);
    k_gemm_proj<<<256, 512, 0, stream>>>(y, WpT, b_proj, out);
}

// Round 11
// 187.565 us; speedup vs baseline: 1.0725x; 1.0725x over previous
//
#include <hip/hip_runtime.h>
#include <hip/hip_bf16.h>

typedef __bf16 bf16;
typedef __bf16 bf16x8 __attribute__((ext_vector_type(8)));
typedef __bf16 bf16x4v __attribute__((ext_vector_type(4)));
typedef float f32x4 __attribute__((ext_vector_type(4)));
typedef float f32x16 __attribute__((ext_vector_type(16)));
typedef float float4v __attribute__((ext_vector_type(4)));
typedef unsigned int uint32x4 __attribute__((ext_vector_type(4)));

#define MFMA16(a, b, c) __builtin_amdgcn_mfma_f32_16x16x32_bf16(a, b, c, 0, 0, 0)
#define MFMA32(a, b, c) __builtin_amdgcn_mfma_f32_32x32x16_bf16(a, b, c, 0, 0, 0)

// q pre-scale: 1/sqrt(64) * log2(e)  (softmax runs in exp2 domain)
#define SCALE_Q 0.1803368801111f

__device__ __forceinline__ void async_load16(const bf16* g, bf16* l) {
    __builtin_amdgcn_global_load_lds(
        (const __attribute__((address_space(1))) void*)g,
        (__attribute__((address_space(3))) void*)l,
        16, 0, 0);
}

__device__ __forceinline__ unsigned int pack2bf(float a, float b) {
    bf16 x = (bf16)a, y = (bf16)b;
    unsigned short ux = __builtin_bit_cast(unsigned short, x);
    unsigned short uy = __builtin_bit_cast(unsigned short, y);
    return (unsigned int)ux | ((unsigned int)uy << 16);
}

// ---------------- fused preprocessing: cast x (+ new_memory copy) + W transposes ----------------
__global__ void k_pre(const float* __restrict__ x, const float* __restrict__ W_attn,
                      const float* __restrict__ W_proj,
                      bf16* __restrict__ xb, float* __restrict__ out_mem,
                      bf16* __restrict__ WaT, bf16* __restrict__ WpT) {
    __shared__ float tile[32][33];
    int bid = blockIdx.x;
    if (bid < 8192) {
        int i = bid * 256 + threadIdx.x;     // float4 index, 2097152 total
        float4v v = ((const float4v*)x)[i];
        bf16x4v o;
        o.x = (bf16)v.x; o.y = (bf16)v.y; o.z = (bf16)v.z; o.w = (bf16)v.w;
        ((bf16x4v*)xb)[i] = o;
        int rem = i & 524287;
        if (rem >= 393216) {
            int b = i >> 19;
            ((float4v*)out_mem)[(size_t)b * 131072 + (rem - 393216)] = v;
        }
        return;
    }
    const float* W;  bf16* WT;  int R, Cc, bx, by;
    if (bid < 8192 + 3072) {
        int idx = bid - 8192;
        W = W_attn; WT = WaT; R = 1024; Cc = 3072; bx = idx % 96; by = idx / 96;
    } else {
        int idx = bid - 11264;
        W = W_proj; WT = WpT; R = 1024; Cc = 1024; bx = idx & 31; by = idx >> 5;
    }
    int r0 = by * 32, c0 = bx * 32;
    int tx = threadIdx.x & 31, ty = threadIdx.x >> 5;
#pragma unroll
    for (int i = 0; i < 32; i += 8)
        tile[ty + i][tx] = W[(size_t)(r0 + ty + i) * Cc + c0 + tx];
    __syncthreads();
#pragma unroll
    for (int i = 0; i < 32; i += 8)
        WT[(size_t)(c0 + ty + i) * R + r0 + tx] = (bf16)tile[tx][ty + i];
}

// ============== 128x128 GEMM, BK=64, counted-vmcnt 2-phase (r9 skeleton) ==============
// 256 thr = 4 waves (2M x 2N). LDS: As[2][128x64] + Bs[2][128x64] = 64KB -> 2 blocks/CU.
// 16 K-tiles; per tile: 16 ds_read_b128 + 32 MFMA + 2 barriers + vmcnt(8) (never 0 mid-loop).
// Slot-involution swizzle: LDS[row][slot] holds G[row][slot^(row&7)] -> 2-way max on b128 reads.
// Staging: thread covers rows (tid>>3)+32i, slot tid&7; loads stay 2 tiles in flight.

#define STAGE64(db, k0) { \
    async_load16(Asrc + (k0),          &As[db][tid8]);         \
    async_load16(Asrc + 32768 + (k0),  &As[db][2048 + tid8]);  \
    async_load16(Asrc + 65536 + (k0),  &As[db][4096 + tid8]);  \
    async_load16(Asrc + 98304 + (k0),  &As[db][6144 + tid8]);  \
    async_load16(Bsrc + (k0),          &Bs[db][tid8]);         \
    async_load16(Bsrc + 32768 + (k0),  &Bs[db][2048 + tid8]);  \
    async_load16(Bsrc + 65536 + (k0),  &Bs[db][4096 + tid8]);  \
    async_load16(Bsrc + 98304 + (k0),  &Bs[db][6144 + tid8]);  }

#define GEMM_BODY64                                                                      \
    STAGE64(0, 0)                                                                        \
    STAGE64(1, 64)                                                                       \
    asm volatile("s_waitcnt vmcnt(8)" ::: "memory");                                     \
    __builtin_amdgcn_sched_barrier(0);                                                   \
    __builtin_amdgcn_s_barrier();                                                        \
    __builtin_amdgcn_sched_barrier(0);                                                   \
    for (int t = 0; t < 16; ++t) {                                                       \
        int db = t & 1;                                                                  \
        _Pragma("unroll")                                                                \
        for (int kc = 0; kc < 2; ++kc) {                                                 \
            bf16x8 af[4], bfr[4];                                                        \
            _Pragma("unroll")                                                            \
            for (int mi = 0; mi < 4; ++mi)                                               \
                af[mi] = *(const bf16x8*)&As[db][(wr * 64 + mi * 16 + lrow) * 64 +       \
                                                 ((kc * 4 + lks) ^ (lrow & 7)) * 8];     \
            _Pragma("unroll")                                                            \
            for (int ni = 0; ni < 4; ++ni)                                               \
                bfr[ni] = *(const bf16x8*)&Bs[db][(wc * 64 + ni * 16 + lrow) * 64 +      \
                                                  ((kc * 4 + lks) ^ (lrow & 7)) * 8];    \
            __builtin_amdgcn_s_setprio(1);                                               \
            _Pragma("unroll")                                                            \
            for (int mi = 0; mi < 4; ++mi)                                               \
                _Pragma("unroll")                                                        \
                for (int ni = 0; ni < 4; ++ni)                                           \
                    acc[mi][ni] = MFMA16(af[mi], bfr[ni], acc[mi][ni]);                  \
            __builtin_amdgcn_s_setprio(0);                                               \
        }                                                                                \
        asm volatile("s_waitcnt lgkmcnt(0)" ::: "memory");                               \
        __builtin_amdgcn_sched_barrier(0);                                               \
        __builtin_amdgcn_s_barrier();     /* all waves done reading buf db */            \
        __builtin_amdgcn_sched_barrier(0);                                               \
        if (t + 2 < 16) {                                                                \
            STAGE64(db, (t + 2) * 64)     /* overwrite just-consumed buffer */           \
            asm volatile("s_waitcnt vmcnt(8)" ::: "memory");   /* tile t+1 landed */     \
        } else {                                                                         \
            asm volatile("s_waitcnt vmcnt(0)" ::: "memory");                             \
        }                                                                                \
        __builtin_amdgcn_sched_barrier(0);                                               \
        __builtin_amdgcn_s_barrier();     /* buf db^1 ready for all */                   \
        __builtin_amdgcn_sched_barrier(0);                                               \
    }

// ---------------- QKV GEMM with fragment-packed scatter epilogue ----------------
__global__ __launch_bounds__(256, 2) void k_gemm_qkv(
    const bf16* __restrict__ A, const bf16* __restrict__ BT,
    const float* __restrict__ bias,
    bf16* __restrict__ qo, bf16* __restrict__ ko, bf16* __restrict__ vo) {
    __shared__ __align__(16) bf16 As[2][8192];
    __shared__ __align__(16) bf16 Bs[2][8192];
    // XCD-chunked swizzle (bijective: 1536 = 8 * 192)
    int orig = blockIdx.y * 24 + blockIdx.x;
    int wg = (orig & 7) * 192 + (orig >> 3);
    int row0 = (wg / 24) * 128;
    int col0 = (wg % 24) * 128;
    int tid = threadIdx.x;
    int lane = tid & 63, w = tid >> 6;
    int wr = w >> 1, wc = w & 1;
    int lrow = lane & 15, lks = lane >> 4;
    int tid8 = tid * 8;
    f32x4 acc[4][4] = {};
    const bf16* Asrc = A + (size_t)(row0 + (tid >> 3)) * 1024 + ((tid & 7) ^ ((tid >> 3) & 7)) * 8;
    const bf16* Bsrc = BT + (size_t)(col0 + (tid >> 3)) * 1024 + ((tid & 7) ^ ((tid >> 3) & 7)) * 8;

    GEMM_BODY64

    int trow = row0 + wr * 64 + lks * 4;
    int tcol = col0 + wc * 64 + lrow;
#pragma unroll
    for (int m = 0; m < 4; ++m)
#pragma unroll
        for (int n = 0; n < 4; ++n) {
            int cg = tcol + n * 16;
            float bi = bias[cg];
#pragma unroll
            for (int j = 0; j < 4; ++j) {
                int rg = trow + m * 16 + j;
                float val = acc[m][n][j] + bi;
                int b = rg >> 11, tt = rg & 2047;
                if (cg < 1024) {
                    int h = cg >> 6, d = cg & 63;
                    size_t base = (size_t)(b * 16 + h) * 131072;
                    size_t idx = base + (size_t)((((tt >> 5) * 4 + (d >> 4)) * 64 + ((d >> 3) & 1) * 32 + (tt & 31)) * 8 + (d & 7));
                    qo[idx] = (bf16)(val * SCALE_Q);
                } else if (cg < 2048) {
                    int c2 = cg - 1024;
                    int h = c2 >> 6, d = c2 & 63;
                    size_t base = (size_t)(b * 16 + h) * 131072;
                    size_t idx = base + (size_t)((((tt >> 5) * 4 + (d >> 4)) * 64 + ((d >> 3) & 1) * 32 + (tt & 31)) * 8 + (d & 7));
                    ko[idx] = (bf16)val;
                } else {
                    int c2 = cg - 2048;
                    int h = c2 >> 6, d = c2 & 63;
                    size_t base = (size_t)(b * 16 + h) * 131072;
                    size_t idx = base + (size_t)(((((tt >> 6) * 4 + ((tt >> 4) & 3)) * 2 + (d >> 5)) * 64 + ((tt >> 3) & 1) * 32 + (d & 31)) * 8 + (tt & 7));
                    vo[idx] = (bf16)val;
                }
            }
        }
}

// ---------------- proj GEMM: BK=64 pipeline, f32 epilogue ----------------
__global__ __launch_bounds__(256, 2) void k_gemm_proj(
    const bf16* __restrict__ A, const bf16* __restrict__ BT,
    const float* __restrict__ bias, float* __restrict__ out) {
    __shared__ __align__(16) bf16 As[2][8192];
    __shared__ __align__(16) bf16 Bs[2][8192];
    // XCD-chunked swizzle (bijective: 512 = 8 * 64)
    int orig = blockIdx.y * 8 + blockIdx.x;
    int wg = (orig & 7) * 64 + (orig >> 3);
    int row0 = (wg >> 3) * 128;
    int col0 = (wg & 7) * 128;
    int tid = threadIdx.x;
    int lane = tid & 63, w = tid >> 6;
    int wr = w >> 1, wc = w & 1;
    int lrow = lane & 15, lks = lane >> 4;
    int tid8 = tid * 8;
    f32x4 acc[4][4] = {};
    const bf16* Asrc = A + (size_t)(row0 + (tid >> 3)) * 1024 + ((tid & 7) ^ ((tid >> 3) & 7)) * 8;
    const bf16* Bsrc = BT + (size_t)(col0 + (tid >> 3)) * 1024 + ((tid & 7) ^ ((tid >> 3) & 7)) * 8;

    GEMM_BODY64

    int trow = row0 + wr * 64 + lks * 4;
    int tcol = col0 + wc * 64 + lrow;
#pragma unroll
    for (int m = 0; m < 4; ++m)
#pragma unroll
        for (int n = 0; n < 4; ++n) {
            int cg = tcol + n * 16;
            float bi = bias[cg];
#pragma unroll
            for (int j = 0; j < 4; ++j) {
                int rg = trow + m * 16 + j;
                out[(size_t)rg * 1024 + cg] = acc[m][n][j] + bi;
            }
        }
}

// ---------------- flash attention (causal), LDS-shared K/V tiles (r7, unchanged) ----------------
__global__ __launch_bounds__(256, 2) void k_attn(
    const bf16* __restrict__ qp, const bf16* __restrict__ kp,
    const bf16* __restrict__ vp, bf16* __restrict__ y) {
    __shared__ __align__(16) bf16 Ks[2][4096];
    __shared__ __align__(16) bf16 Vs[2][4096];
    int bh = blockIdx.y;
    int b = bh >> 4;
    int lane = threadIdx.x & 63, w = threadIdx.x >> 6;
    int tl = lane & 31, hi = lane >> 5;
    int lane8 = lane * 8;
    const bf16* Qb = qp + (size_t)bh * 131072;
    const bf16* Kb = kp + (size_t)bh * 131072;
    const bf16* Vb = vp + (size_t)bh * 131072;

    for (int qpass = 0; qpass < 2; ++qpass) {
        int qt0 = (qpass ? 15 - (int)blockIdx.x : (int)blockIdx.x) * 128;
        int trow0 = qt0 + w * 32;
        int t_g = trow0 + tl;

        bf16x8 qf[4];
        int qs = (trow0 >> 5) * 4;
#pragma unroll
        for (int kc = 0; kc < 4; ++kc)
            qf[kc] = *(const bf16x8*)&Qb[(qs + kc) * 512 + lane8];

        f32x16 o[2] = {};
        float m = -1e30f, l = 0.f;
        int ntb = (qt0 >> 6) + 2;
        int cur = 0;

#pragma unroll
        for (int i = 0; i < 2; ++i) {
            int u = 2 * w + i;
            async_load16(Kb + (size_t)u * 512 + lane8, &Ks[0][u * 512]);
            async_load16(Vb + (size_t)u * 512 + lane8, &Vs[0][u * 512]);
        }
        __syncthreads();

        for (int ti = 0; ti < ntb; ++ti) {
            int s0 = ti * 64;
            if (ti + 1 < ntb) {
#pragma unroll
                for (int i = 0; i < 2; ++i) {
                    int u = 2 * w + i;
                    async_load16(Kb + (size_t)((ti + 1) * 8 + u) * 512 + lane8, &Ks[cur ^ 1][u * 512]);
                    async_load16(Vb + (size_t)((ti + 1) * 8 + u) * 512 + lane8, &Vs[cur ^ 1][u * 512]);
                }
            }
            if (s0 < trow0 + 32) {
                f32x16 accs[2] = {};
                __builtin_amdgcn_s_setprio(1);
#pragma unroll
                for (int st = 0; st < 2; ++st)
#pragma unroll
                    for (int kc = 0; kc < 4; ++kc) {
                        bf16x8 kf = *(const bf16x8*)&Ks[cur][(st * 4 + kc) * 512 + lane8];
                        accs[st] = MFMA32(kf, qf[kc], accs[st]);
                    }
                __builtin_amdgcn_s_setprio(0);

                if (s0 + 63 > trow0) {
#pragma unroll
                    for (int st = 0; st < 2; ++st)
#pragma unroll
                        for (int r = 0; r < 16; ++r) {
                            int s = s0 + st * 32 + (r & 3) + 8 * (r >> 2) + 4 * hi;
                            if (s > t_g) accs[st][r] = -1e30f;
                        }
                }
                float pmax = -1e30f;
#pragma unroll
                for (int st = 0; st < 2; ++st)
#pragma unroll
                    for (int r = 0; r < 16; ++r)
                        pmax = fmaxf(pmax, accs[st][r]);
                pmax = fmaxf(pmax, __shfl_xor(pmax, 32));
                if (!__all(pmax <= m + 8.0f)) {
                    float mn = fmaxf(m, pmax);
                    float corr = __builtin_amdgcn_exp2f(m - mn);
                    m = mn;
                    l *= corr;
#pragma unroll
                    for (int dt = 0; dt < 2; ++dt)
#pragma unroll
                        for (int r = 0; r < 16; ++r)
                            o[dt][r] *= corr;
                }
                float ls = 0.f;
#pragma unroll
                for (int st = 0; st < 2; ++st)
#pragma unroll
                    for (int r = 0; r < 16; ++r) {
                        float p = __builtin_amdgcn_exp2f(accs[st][r] - m);
                        accs[st][r] = p;
                        ls += p;
                    }
                ls += __shfl_xor(ls, 32);
                l += ls;

                unsigned int pk[16];
#pragma unroll
                for (int st = 0; st < 2; ++st)
#pragma unroll
                    for (int q = 0; q < 8; ++q)
                        pk[st * 8 + q] = pack2bf(accs[st][2 * q], accs[st][2 * q + 1]);
                unsigned int rv[8];
#pragma unroll
                for (int st = 0; st < 2; ++st)
#pragma unroll
                    for (int i = 0; i < 4; ++i) {
                        int base = st * 8 + (i < 2 ? i : i + 2);
                        unsigned int send = hi ? pk[base] : pk[base + 2];
                        rv[st * 4 + i] = __shfl_xor(send, 32);
                    }
                __builtin_amdgcn_s_setprio(1);
#pragma unroll
                for (int c = 0; c < 4; ++c) {
                    const int st = c >> 1, c2 = c & 1;
                    uint32x4 pw;
                    pw.x = hi ? rv[st * 4 + 2 * c2]     : pk[st * 8 + 4 * c2];
                    pw.y = hi ? rv[st * 4 + 2 * c2 + 1] : pk[st * 8 + 4 * c2 + 1];
                    pw.z = hi ? pk[st * 8 + 4 * c2 + 2] : rv[st * 4 + 2 * c2];
                    pw.w = hi ? pk[st * 8 + 4 * c2 + 3] : rv[st * 4 + 2 * c2 + 1];
                    bf16x8 pf = __builtin_bit_cast(bf16x8, pw);
#pragma unroll
                    for (int dt = 0; dt < 2; ++dt) {
                        bf16x8 vf = *(const bf16x8*)&Vs[cur][(c * 2 + dt) * 512 + lane8];
                        o[dt] = MFMA32(vf, pf, o[dt]);
                    }
                }
                __builtin_amdgcn_s_setprio(0);
            }
            __syncthreads();
            cur ^= 1;
        }

        int hcol = (bh & 15) * 64;
        float inv = 1.0f / l;
        bf16* yr = y + (size_t)(b * 2048 + t_g) * 1024 + hcol;
#pragma unroll
        for (int dt = 0; dt < 2; ++dt)
#pragma unroll
            for (int rq = 0; rq < 4; ++rq) {
                bf16x4v ov;
#pragma unroll
                for (int ri = 0; ri < 4; ++ri)
                    ov[ri] = (bf16)(o[dt][rq * 4 + ri] * inv);
                *(bf16x4v*)&yr[dt * 32 + rq * 8 + hi * 4] = ov;
            }
    }
}

extern "C" void kernel_launch(void* const* d_in, const int* in_sizes, int n_in,
                              void* d_out, int out_size, void* d_ws, size_t ws_size,
                              hipStream_t stream) {
    const float* x = (const float*)d_in[0];
    const float* W_attn = (const float*)d_in[1];
    const float* b_attn = (const float*)d_in[2];
    const float* W_proj = (const float*)d_in[3];
    const float* b_proj = (const float*)d_in[4];
    float* out = (float*)d_out;
    float* out_mem = out + (size_t)8388608;

    char* ws = (char*)d_ws;
    bf16* xb  = (bf16*)(ws);                         // 16MB  [8192][1024]
    bf16* WaT = (bf16*)(ws + ((size_t)16 << 20));    // 6MB   [3072][1024]
    bf16* WpT = (bf16*)(ws + ((size_t)22 << 20));    // 2MB   [1024][1024]
    bf16* q   = (bf16*)(ws + ((size_t)24 << 20));    // 16MB  packed frags
    bf16* k   = (bf16*)(ws + ((size_t)40 << 20));    // 16MB  packed frags
    bf16* vT  = (bf16*)(ws + ((size_t)56 << 20));    // 16MB  packed frags
    bf16* y   = (bf16*)(ws + ((size_t)72 << 20));    // 16MB  [8192][1024]

    k_pre<<<12288, 256, 0, stream>>>(x, W_attn, W_proj, xb, out_mem, WaT, WpT);
    k_gemm_qkv<<<dim3(24, 64), 256, 0, stream>>>(xb, WaT, b_attn, q, k, vT);
    k_attn<<<dim3(8, 64), 256, 0, stream>>>(q, k, vT, y);
    k_gemm_proj<<<dim3(8, 64), 256, 0, stream>>>(y, WpT, b_proj, out);
}

// Round 12
// 184.119 us; speedup vs baseline: 1.0925x; 1.0187x over previous
//
#include <hip/hip_runtime.h>
#include <hip/hip_bf16.h>

typedef __bf16 bf16;
typedef __bf16 bf16x8 __attribute__((ext_vector_type(8)));
typedef __bf16 bf16x4v __attribute__((ext_vector_type(4)));
typedef float f32x4 __attribute__((ext_vector_type(4)));
typedef float f32x16 __attribute__((ext_vector_type(16)));
typedef float float4v __attribute__((ext_vector_type(4)));
typedef unsigned int uint32x4 __attribute__((ext_vector_type(4)));

#define MFMA16(a, b, c) __builtin_amdgcn_mfma_f32_16x16x32_bf16(a, b, c, 0, 0, 0)
#define MFMA32(a, b, c) __builtin_amdgcn_mfma_f32_32x32x16_bf16(a, b, c, 0, 0, 0)

// q pre-scale: 1/sqrt(64) * log2(e)  (softmax runs in exp2 domain)
#define SCALE_Q 0.1803368801111f

__device__ __forceinline__ void async_load16(const bf16* g, bf16* l) {
    __builtin_amdgcn_global_load_lds(
        (const __attribute__((address_space(1))) void*)g,
        (__attribute__((address_space(3))) void*)l,
        16, 0, 0);
}

__device__ __forceinline__ unsigned int pack2bf(float a, float b) {
    bf16 x = (bf16)a, y = (bf16)b;
    unsigned short ux = __builtin_bit_cast(unsigned short, x);
    unsigned short uy = __builtin_bit_cast(unsigned short, y);
    return (unsigned int)ux | ((unsigned int)uy << 16);
}

// ---------------- fused preprocessing: cast x (+ new_memory copy) + W transposes ----------------
__global__ void k_pre(const float* __restrict__ x, const float* __restrict__ W_attn,
                      const float* __restrict__ W_proj,
                      bf16* __restrict__ xb, float* __restrict__ out_mem,
                      bf16* __restrict__ WaT, bf16* __restrict__ WpT) {
    __shared__ float tile[32][33];
    int bid = blockIdx.x;
    if (bid < 8192) {
        int i = bid * 256 + threadIdx.x;     // float4 index, 2097152 total
        float4v v = ((const float4v*)x)[i];
        bf16x4v o;
        o.x = (bf16)v.x; o.y = (bf16)v.y; o.z = (bf16)v.z; o.w = (bf16)v.w;
        ((bf16x4v*)xb)[i] = o;
        int rem = i & 524287;
        if (rem >= 393216) {
            int b = i >> 19;
            ((float4v*)out_mem)[(size_t)b * 131072 + (rem - 393216)] = v;
        }
        return;
    }
    const float* W;  bf16* WT;  int R, Cc, bx, by;
    if (bid < 8192 + 3072) {
        int idx = bid - 8192;
        W = W_attn; WT = WaT; R = 1024; Cc = 3072; bx = idx % 96; by = idx / 96;
    } else {
        int idx = bid - 11264;
        W = W_proj; WT = WpT; R = 1024; Cc = 1024; bx = idx & 31; by = idx >> 5;
    }
    int r0 = by * 32, c0 = bx * 32;
    int tx = threadIdx.x & 31, ty = threadIdx.x >> 5;
#pragma unroll
    for (int i = 0; i < 32; i += 8)
        tile[ty + i][tx] = W[(size_t)(r0 + ty + i) * Cc + c0 + tx];
    __syncthreads();
#pragma unroll
    for (int i = 0; i < 32; i += 8)
        WT[(size_t)(c0 + ty + i) * R + r0 + tx] = (bf16)tile[tx][ty + i];
}

// ============== 128x128 GEMM, BK=64, counted-vmcnt 2-phase (r9 skeleton) ==============
#define STAGE64(db, k0) { \
    async_load16(Asrc + (k0),          &As[db][tid8]);         \
    async_load16(Asrc + 32768 + (k0),  &As[db][2048 + tid8]);  \
    async_load16(Asrc + 65536 + (k0),  &As[db][4096 + tid8]);  \
    async_load16(Asrc + 98304 + (k0),  &As[db][6144 + tid8]);  \
    async_load16(Bsrc + (k0),          &Bs[db][tid8]);         \
    async_load16(Bsrc + 32768 + (k0),  &Bs[db][2048 + tid8]);  \
    async_load16(Bsrc + 65536 + (k0),  &Bs[db][4096 + tid8]);  \
    async_load16(Bsrc + 98304 + (k0),  &Bs[db][6144 + tid8]);  }

#define GEMM_BODY64                                                                      \
    STAGE64(0, 0)                                                                        \
    STAGE64(1, 64)                                                                       \
    asm volatile("s_waitcnt vmcnt(8)" ::: "memory");                                     \
    __builtin_amdgcn_sched_barrier(0);                                                   \
    __builtin_amdgcn_s_barrier();                                                        \
    __builtin_amdgcn_sched_barrier(0);                                                   \
    for (int t = 0; t < 16; ++t) {                                                       \
        int db = t & 1;                                                                  \
        _Pragma("unroll")                                                                \
        for (int kc = 0; kc < 2; ++kc) {                                                 \
            bf16x8 af[4], bfr[4];                                                        \
            _Pragma("unroll")                                                            \
            for (int mi = 0; mi < 4; ++mi)                                               \
                af[mi] = *(const bf16x8*)&As[db][(wr * 64 + mi * 16 + lrow) * 64 +       \
                                                 ((kc * 4 + lks) ^ (lrow & 7)) * 8];     \
            _Pragma("unroll")                                                            \
            for (int ni = 0; ni < 4; ++ni)                                               \
                bfr[ni] = *(const bf16x8*)&Bs[db][(wc * 64 + ni * 16 + lrow) * 64 +      \
                                                  ((kc * 4 + lks) ^ (lrow & 7)) * 8];    \
            __builtin_amdgcn_s_setprio(1);                                               \
            _Pragma("unroll")                                                            \
            for (int mi = 0; mi < 4; ++mi)                                               \
                _Pragma("unroll")                                                        \
                for (int ni = 0; ni < 4; ++ni)                                           \
                    acc[mi][ni] = MFMA16(af[mi], bfr[ni], acc[mi][ni]);                  \
            __builtin_amdgcn_s_setprio(0);                                               \
        }                                                                                \
        asm volatile("s_waitcnt lgkmcnt(0)" ::: "memory");                               \
        __builtin_amdgcn_sched_barrier(0);                                               \
        __builtin_amdgcn_s_barrier();     /* all waves done reading buf db */            \
        __builtin_amdgcn_sched_barrier(0);                                               \
        if (t + 2 < 16) {                                                                \
            STAGE64(db, (t + 2) * 64)     /* overwrite just-consumed buffer */           \
            asm volatile("s_waitcnt vmcnt(8)" ::: "memory");   /* tile t+1 landed */     \
        } else {                                                                         \
            asm volatile("s_waitcnt vmcnt(0)" ::: "memory");                             \
        }                                                                                \
        __builtin_amdgcn_sched_barrier(0);                                               \
        __builtin_amdgcn_s_barrier();     /* buf db^1 ready for all */                   \
        __builtin_amdgcn_sched_barrier(0);                                               \
    }

// ---------------- QKV GEMM with fragment-packed scatter epilogue ----------------
__global__ __launch_bounds__(256, 2) void k_gemm_qkv(
    const bf16* __restrict__ A, const bf16* __restrict__ BT,
    const float* __restrict__ bias,
    bf16* __restrict__ qo, bf16* __restrict__ ko, bf16* __restrict__ vo) {
    __shared__ __align__(16) bf16 As[2][8192];
    __shared__ __align__(16) bf16 Bs[2][8192];
    // XCD-chunked swizzle (bijective: 1536 = 8 * 192)
    int orig = blockIdx.y * 24 + blockIdx.x;
    int wg = (orig & 7) * 192 + (orig >> 3);
    int row0 = (wg / 24) * 128;
    int col0 = (wg % 24) * 128;
    int tid = threadIdx.x;
    int lane = tid & 63, w = tid >> 6;
    int wr = w >> 1, wc = w & 1;
    int lrow = lane & 15, lks = lane >> 4;
    int tid8 = tid * 8;
    f32x4 acc[4][4] = {};
    const bf16* Asrc = A + (size_t)(row0 + (tid >> 3)) * 1024 + ((tid & 7) ^ ((tid >> 3) & 7)) * 8;
    const bf16* Bsrc = BT + (size_t)(col0 + (tid >> 3)) * 1024 + ((tid & 7) ^ ((tid >> 3) & 7)) * 8;

    GEMM_BODY64

    int trow = row0 + wr * 64 + lks * 4;
    int tcol = col0 + wc * 64 + lrow;
#pragma unroll
    for (int m = 0; m < 4; ++m)
#pragma unroll
        for (int n = 0; n < 4; ++n) {
            int cg = tcol + n * 16;
            float bi = bias[cg];
#pragma unroll
            for (int j = 0; j < 4; ++j) {
                int rg = trow + m * 16 + j;
                float val = acc[m][n][j] + bi;
                int b = rg >> 11, tt = rg & 2047;
                if (cg < 1024) {
                    int h = cg >> 6, d = cg & 63;
                    size_t base = (size_t)(b * 16 + h) * 131072;
                    size_t idx = base + (size_t)((((tt >> 5) * 4 + (d >> 4)) * 64 + ((d >> 3) & 1) * 32 + (tt & 31)) * 8 + (d & 7));
                    qo[idx] = (bf16)(val * SCALE_Q);
                } else if (cg < 2048) {
                    int c2 = cg - 1024;
                    int h = c2 >> 6, d = c2 & 63;
                    size_t base = (size_t)(b * 16 + h) * 131072;
                    size_t idx = base + (size_t)((((tt >> 5) * 4 + (d >> 4)) * 64 + ((d >> 3) & 1) * 32 + (tt & 31)) * 8 + (d & 7));
                    ko[idx] = (bf16)val;
                } else {
                    int c2 = cg - 2048;
                    int h = c2 >> 6, d = c2 & 63;
                    size_t base = (size_t)(b * 16 + h) * 131072;
                    size_t idx = base + (size_t)(((((tt >> 6) * 4 + ((tt >> 4) & 3)) * 2 + (d >> 5)) * 64 + ((tt >> 3) & 1) * 32 + (d & 31)) * 8 + (tt & 7));
                    vo[idx] = (bf16)val;
                }
            }
        }
}

// ---------------- proj GEMM: BK=64 pipeline, f32 epilogue ----------------
__global__ __launch_bounds__(256, 2) void k_gemm_proj(
    const bf16* __restrict__ A, const bf16* __restrict__ BT,
    const float* __restrict__ bias, float* __restrict__ out) {
    __shared__ __align__(16) bf16 As[2][8192];
    __shared__ __align__(16) bf16 Bs[2][8192];
    // XCD-chunked swizzle (bijective: 512 = 8 * 64)
    int orig = blockIdx.y * 8 + blockIdx.x;
    int wg = (orig & 7) * 64 + (orig >> 3);
    int row0 = (wg >> 3) * 128;
    int col0 = (wg & 7) * 128;
    int tid = threadIdx.x;
    int lane = tid & 63, w = tid >> 6;
    int wr = w >> 1, wc = w & 1;
    int lrow = lane & 15, lks = lane >> 4;
    int tid8 = tid * 8;
    f32x4 acc[4][4] = {};
    const bf16* Asrc = A + (size_t)(row0 + (tid >> 3)) * 1024 + ((tid & 7) ^ ((tid >> 3) & 7)) * 8;
    const bf16* Bsrc = BT + (size_t)(col0 + (tid >> 3)) * 1024 + ((tid & 7) ^ ((tid >> 3) & 7)) * 8;

    GEMM_BODY64

    int trow = row0 + wr * 64 + lks * 4;
    int tcol = col0 + wc * 64 + lrow;
#pragma unroll
    for (int m = 0; m < 4; ++m)
#pragma unroll
        for (int n = 0; n < 4; ++n) {
            int cg = tcol + n * 16;
            float bi = bias[cg];
#pragma unroll
            for (int j = 0; j < 4; ++j) {
                int rg = trow + m * 16 + j;
                out[(size_t)rg * 1024 + cg] = acc[m][n][j] + bi;
            }
        }
}

// ---------------- flash attention (causal), LDS-shared K/V, XCD head-grouping ----------------
// 1D grid 512: xcd = id&7, bx = (id>>3)&7, bh = (id&7) + 8*(id>>6).
// All 8 blocks of head bh share linear ids ≡ bh (mod 8) -> same XCD (round-robin
// dispatch), temporally adjacent -> K/V (512KB/head) stays hot in that XCD's 4MB L2.
__global__ __launch_bounds__(256, 2) void k_attn(
    const bf16* __restrict__ qp, const bf16* __restrict__ kp,
    const bf16* __restrict__ vp, bf16* __restrict__ y) {
    __shared__ __align__(16) bf16 Ks[2][4096];
    __shared__ __align__(16) bf16 Vs[2][4096];
    int id = blockIdx.x;
    int bxp = (id >> 3) & 7;
    int bh = (id & 7) + 8 * (id >> 6);
    int b = bh >> 4;
    int lane = threadIdx.x & 63, w = threadIdx.x >> 6;
    int tl = lane & 31, hi = lane >> 5;
    int lane8 = lane * 8;
    const bf16* Qb = qp + (size_t)bh * 131072;
    const bf16* Kb = kp + (size_t)bh * 131072;
    const bf16* Vb = vp + (size_t)bh * 131072;

    for (int qpass = 0; qpass < 2; ++qpass) {
        int qt0 = (qpass ? 15 - bxp : bxp) * 128;
        int trow0 = qt0 + w * 32;
        int t_g = trow0 + tl;

        bf16x8 qf[4];
        int qs = (trow0 >> 5) * 4;
#pragma unroll
        for (int kc = 0; kc < 4; ++kc)
            qf[kc] = *(const bf16x8*)&Qb[(qs + kc) * 512 + lane8];

        f32x16 o[2] = {};
        float m = -1e30f, l = 0.f;
        int ntb = (qt0 >> 6) + 2;
        int cur = 0;

#pragma unroll
        for (int i = 0; i < 2; ++i) {
            int u = 2 * w + i;
            async_load16(Kb + (size_t)u * 512 + lane8, &Ks[0][u * 512]);
            async_load16(Vb + (size_t)u * 512 + lane8, &Vs[0][u * 512]);
        }
        __syncthreads();

        for (int ti = 0; ti < ntb; ++ti) {
            int s0 = ti * 64;
            if (ti + 1 < ntb) {
#pragma unroll
                for (int i = 0; i < 2; ++i) {
                    int u = 2 * w + i;
                    async_load16(Kb + (size_t)((ti + 1) * 8 + u) * 512 + lane8, &Ks[cur ^ 1][u * 512]);
                    async_load16(Vb + (size_t)((ti + 1) * 8 + u) * 512 + lane8, &Vs[cur ^ 1][u * 512]);
                }
            }
            if (s0 < trow0 + 32) {
                f32x16 accs[2] = {};
                __builtin_amdgcn_s_setprio(1);
#pragma unroll
                for (int st = 0; st < 2; ++st)
#pragma unroll
                    for (int kc = 0; kc < 4; ++kc) {
                        bf16x8 kf = *(const bf16x8*)&Ks[cur][(st * 4 + kc) * 512 + lane8];
                        accs[st] = MFMA32(kf, qf[kc], accs[st]);
                    }
                __builtin_amdgcn_s_setprio(0);

                if (s0 + 63 > trow0) {
#pragma unroll
                    for (int st = 0; st < 2; ++st)
#pragma unroll
                        for (int r = 0; r < 16; ++r) {
                            int s = s0 + st * 32 + (r & 3) + 8 * (r >> 2) + 4 * hi;
                            if (s > t_g) accs[st][r] = -1e30f;
                        }
                }
                float pmax = -1e30f;
#pragma unroll
                for (int st = 0; st < 2; ++st)
#pragma unroll
                    for (int r = 0; r < 16; ++r)
                        pmax = fmaxf(pmax, accs[st][r]);
                pmax = fmaxf(pmax, __shfl_xor(pmax, 32));
                if (!__all(pmax <= m + 8.0f)) {
                    float mn = fmaxf(m, pmax);
                    float corr = __builtin_amdgcn_exp2f(m - mn);
                    m = mn;
                    l *= corr;
#pragma unroll
                    for (int dt = 0; dt < 2; ++dt)
#pragma unroll
                        for (int r = 0; r < 16; ++r)
                            o[dt][r] *= corr;
                }
                float ls = 0.f;
#pragma unroll
                for (int st = 0; st < 2; ++st)
#pragma unroll
                    for (int r = 0; r < 16; ++r) {
                        float p = __builtin_amdgcn_exp2f(accs[st][r] - m);
                        accs[st][r] = p;
                        ls += p;
                    }
                ls += __shfl_xor(ls, 32);
                l += ls;

                unsigned int pk[16];
#pragma unroll
                for (int st = 0; st < 2; ++st)
#pragma unroll
                    for (int q = 0; q < 8; ++q)
                        pk[st * 8 + q] = pack2bf(accs[st][2 * q], accs[st][2 * q + 1]);
                unsigned int rv[8];
#pragma unroll
                for (int st = 0; st < 2; ++st)
#pragma unroll
                    for (int i = 0; i < 4; ++i) {
                        int base = st * 8 + (i < 2 ? i : i + 2);
                        unsigned int send = hi ? pk[base] : pk[base + 2];
                        rv[st * 4 + i] = __shfl_xor(send, 32);
                    }
                __builtin_amdgcn_s_setprio(1);
#pragma unroll
                for (int c = 0; c < 4; ++c) {
                    const int st = c >> 1, c2 = c & 1;
                    uint32x4 pw;
                    pw.x = hi ? rv[st * 4 + 2 * c2]     : pk[st * 8 + 4 * c2];
                    pw.y = hi ? rv[st * 4 + 2 * c2 + 1] : pk[st * 8 + 4 * c2 + 1];
                    pw.z = hi ? pk[st * 8 + 4 * c2 + 2] : rv[st * 4 + 2 * c2];
                    pw.w = hi ? pk[st * 8 + 4 * c2 + 3] : rv[st * 4 + 2 * c2 + 1];
                    bf16x8 pf = __builtin_bit_cast(bf16x8, pw);
#pragma unroll
                    for (int dt = 0; dt < 2; ++dt) {
                        bf16x8 vf = *(const bf16x8*)&Vs[cur][(c * 2 + dt) * 512 + lane8];
                        o[dt] = MFMA32(vf, pf, o[dt]);
                    }
                }
                __builtin_amdgcn_s_setprio(0);
            }
            __syncthreads();
            cur ^= 1;
        }

        int hcol = (bh & 15) * 64;
        float inv = 1.0f / l;
        bf16* yr = y + (size_t)(b * 2048 + t_g) * 1024 + hcol;
#pragma unroll
        for (int dt = 0; dt < 2; ++dt)
#pragma unroll
            for (int rq = 0; rq < 4; ++rq) {
                bf16x4v ov;
#pragma unroll
                for (int ri = 0; ri < 4; ++ri)
                    ov[ri] = (bf16)(o[dt][rq * 4 + ri] * inv);
                *(bf16x4v*)&yr[dt * 32 + rq * 8 + hi * 4] = ov;
            }
    }
}

extern "C" void kernel_launch(void* const* d_in, const int* in_sizes, int n_in,
                              void* d_out, int out_size, void* d_ws, size_t ws_size,
                              hipStream_t stream) {
    const float* x = (const float*)d_in[0];
    const float* W_attn = (const float*)d_in[1];
    const float* b_attn = (const float*)d_in[2];
    const float* W_proj = (const float*)d_in[3];
    const float* b_proj = (const float*)d_in[4];
    float* out = (float*)d_out;
    float* out_mem = out + (size_t)8388608;

    char* ws = (char*)d_ws;
    bf16* xb  = (bf16*)(ws);                         // 16MB  [8192][1024]
    bf16* WaT = (bf16*)(ws + ((size_t)16 << 20));    // 6MB   [3072][1024]
    bf16* WpT = (bf16*)(ws + ((size_t)22 << 20));    // 2MB   [1024][1024]
    bf16* q   = (bf16*)(ws + ((size_t)24 << 20));    // 16MB  packed frags
    bf16* k   = (bf16*)(ws + ((size_t)40 << 20));    // 16MB  packed frags
    bf16* vT  = (bf16*)(ws + ((size_t)56 << 20));    // 16MB  packed frags
    bf16* y   = (bf16*)(ws + ((size_t)72 << 20));    // 16MB  [8192][1024]

    k_pre<<<12288, 256, 0, stream>>>(x, W_attn, W_proj, xb, out_mem, WaT, WpT);
    k_gemm_qkv<<<dim3(24, 64), 256, 0, stream>>>(xb, WaT, b_attn, q, k, vT);
    k_attn<<<512, 256, 0, stream>>>(q, k, vT, y);
    k_gemm_proj<<<dim3(8, 64), 256, 0, stream>>>(y, WpT, b_proj, out);
}

// Round 13
// 179.871 us; speedup vs baseline: 1.1183x; 1.0236x over previous
//
#include <hip/hip_runtime.h>
#include <hip/hip_bf16.h>

typedef __bf16 bf16;
typedef __bf16 bf16x8 __attribute__((ext_vector_type(8)));
typedef __bf16 bf16x4v __attribute__((ext_vector_type(4)));
typedef float f32x4 __attribute__((ext_vector_type(4)));
typedef float f32x16 __attribute__((ext_vector_type(16)));
typedef float float4v __attribute__((ext_vector_type(4)));
typedef unsigned int uint32x4 __attribute__((ext_vector_type(4)));

#define MFMA16(a, b, c) __builtin_amdgcn_mfma_f32_16x16x32_bf16(a, b, c, 0, 0, 0)
#define MFMA32(a, b, c) __builtin_amdgcn_mfma_f32_32x32x16_bf16(a, b, c, 0, 0, 0)

// q pre-scale: 1/sqrt(64) * log2(e)  (softmax runs in exp2 domain)
#define SCALE_Q 0.1803368801111f

__device__ __forceinline__ void async_load16(const bf16* g, bf16* l) {
    __builtin_amdgcn_global_load_lds(
        (const __attribute__((address_space(1))) void*)g,
        (__attribute__((address_space(3))) void*)l,
        16, 0, 0);
}

__device__ __forceinline__ unsigned int pack2bf(float a, float b) {
    bf16 x = (bf16)a, y = (bf16)b;
    unsigned short ux = __builtin_bit_cast(unsigned short, x);
    unsigned short uy = __builtin_bit_cast(unsigned short, y);
    return (unsigned int)ux | ((unsigned int)uy << 16);
}

// =================== fragment-packed layout ===================
// Element (row t, k) of a [T][K] bf16 matrix lives at:
//   line = (t>>4)*(K/32) + (k>>5);  lane = (t&15) + 16*((k>>3)&3);  j = k&7
//   idx  = line*512 + lane*8 + j
// One MFMA A/B fragment (16 rows x 32 k) = one 1KB line = base + lane*16B.

// ---------------- fused preprocessing: pack x / W_attn^T / W_proj^T (+ new_memory) ----------------
__global__ void k_pre(const float* __restrict__ x, const float* __restrict__ W_attn,
                      const float* __restrict__ W_proj,
                      bf16* __restrict__ xpk, float* __restrict__ out_mem,
                      bf16* __restrict__ Wapk, bf16* __restrict__ Wppk) {
    int bid = blockIdx.x, tid = threadIdx.x;
    int lane = tid & 63;
    if (bid < 4096) {
        // x [8192][1024] -> packed A (16384 lines); fused new_memory copy
        int line = bid * 4 + (tid >> 6);
        int slab = line >> 5, kc = line & 31;
        int t = slab * 16 + (lane & 15);
        int k = kc * 32 + (lane >> 4) * 8;
        const float* src = x + (size_t)t * 1024 + k;
        float4v v0 = *(const float4v*)src;
        float4v v1 = *(const float4v*)(src + 4);
        bf16x8 o;
        o[0] = (bf16)v0.x; o[1] = (bf16)v0.y; o[2] = (bf16)v0.z; o[3] = (bf16)v0.w;
        o[4] = (bf16)v1.x; o[5] = (bf16)v1.y; o[6] = (bf16)v1.z; o[7] = (bf16)v1.w;
        *(bf16x8*)(xpk + (size_t)line * 512 + lane * 8) = o;
        int tb = t & 2047;
        if (tb >= 1536) {
            float* dst = out_mem + ((size_t)(t >> 11) * 512 + (tb - 1536)) * 1024 + k;
            *(float4v*)dst = v0;
            *(float4v*)(dst + 4) = v1;
        }
    } else if (bid < 4096 + 1536) {
        // W_attn [1024][3072] -> packed B^T (cols n as rows): 6144 lines
        int line = (bid - 4096) * 4 + (tid >> 6);
        int slab = line >> 5, kc = line & 31;
        int n = slab * 16 + (lane & 15);
        int k = kc * 32 + (lane >> 4) * 8;
        bf16x8 o;
#pragma unroll
        for (int j = 0; j < 8; ++j)
            o[j] = (bf16)W_attn[(size_t)(k + j) * 3072 + n];
        *(bf16x8*)(Wapk + (size_t)line * 512 + lane * 8) = o;
    } else {
        // W_proj [1024][1024] -> packed B^T: 2048 lines
        int line = (bid - 5632) * 4 + (tid >> 6);
        int slab = line >> 5, kc = line & 31;
        int n = slab * 16 + (lane & 15);
        int k = kc * 32 + (lane >> 4) * 8;
        bf16x8 o;
#pragma unroll
        for (int j = 0; j < 8; ++j)
            o[j] = (bf16)W_proj[(size_t)(k + j) * 1024 + n];
        *(bf16x8*)(Wppk + (size_t)line * 512 + lane * 8) = o;
    }
}

// =================== LDS-free, barrier-free 128x128 GEMM body ===================
// 4 waves (2M x 2N), each 64x64 out = 4x4 16^2 frags. All operand loads are
// contiguous base+lane*16B (1KB/wave). Register 2-deep double buffer; waves
// fully independent (setprio pays in this regime, m191).
#define GEMM_NOLDS_BODY                                                                  \
    const bf16* Ab[4]; const bf16* Bb[4];                                                \
    _Pragma("unroll")                                                                    \
    for (int m = 0; m < 4; ++m)                                                          \
        Ab[m] = Apk + (size_t)(((row0 >> 4) + wr * 4 + m) * 32) * 512 + lane * 8;        \
    _Pragma("unroll")                                                                    \
    for (int n = 0; n < 4; ++n)                                                          \
        Bb[n] = Bpk + (size_t)(((col0 >> 4) + wc * 4 + n) * 32) * 512 + lane * 8;        \
    f32x4 acc[4][4] = {};                                                                \
    bf16x8 a0[4], b0[4], a1[4], b1[4];                                                   \
    _Pragma("unroll")                                                                    \
    for (int m = 0; m < 4; ++m) a0[m] = *(const bf16x8*)(Ab[m]);                         \
    _Pragma("unroll")                                                                    \
    for (int n = 0; n < 4; ++n) b0[n] = *(const bf16x8*)(Bb[n]);                         \
    for (int t = 0; t < 16; ++t) {                                                       \
        int o1 = (2 * t + 1) * 512;                                                      \
        _Pragma("unroll")                                                                \
        for (int m = 0; m < 4; ++m) a1[m] = *(const bf16x8*)(Ab[m] + o1);                \
        _Pragma("unroll")                                                                \
        for (int n = 0; n < 4; ++n) b1[n] = *(const bf16x8*)(Bb[n] + o1);                \
        __builtin_amdgcn_s_setprio(1);                                                   \
        _Pragma("unroll")                                                                \
        for (int m = 0; m < 4; ++m)                                                      \
            _Pragma("unroll")                                                            \
            for (int n = 0; n < 4; ++n)                                                  \
                acc[m][n] = MFMA16(a0[m], b0[n], acc[m][n]);                             \
        __builtin_amdgcn_s_setprio(0);                                                   \
        if (t < 15) {                                                                    \
            int o2 = (2 * t + 2) * 512;                                                  \
            _Pragma("unroll")                                                            \
            for (int m = 0; m < 4; ++m) a0[m] = *(const bf16x8*)(Ab[m] + o2);            \
            _Pragma("unroll")                                                            \
            for (int n = 0; n < 4; ++n) b0[n] = *(const bf16x8*)(Bb[n] + o2);            \
        }                                                                                \
        __builtin_amdgcn_s_setprio(1);                                                   \
        _Pragma("unroll")                                                                \
        for (int m = 0; m < 4; ++m)                                                      \
            _Pragma("unroll")                                                            \
            for (int n = 0; n < 4; ++n)                                                  \
                acc[m][n] = MFMA16(a1[m], b1[n], acc[m][n]);                             \
        __builtin_amdgcn_s_setprio(0);                                                   \
    }

// ---------------- QKV GEMM with fragment-packed scatter epilogue ----------------
__global__ __launch_bounds__(256, 2) void k_gemm_qkv(
    const bf16* __restrict__ Apk, const bf16* __restrict__ Bpk,
    const float* __restrict__ bias,
    bf16* __restrict__ qo, bf16* __restrict__ ko, bf16* __restrict__ vo) {
    // XCD-chunked swizzle (bijective: 1536 = 8 * 192)
    int orig = blockIdx.x;
    int wg = (orig & 7) * 192 + (orig >> 3);
    int row0 = (wg / 24) * 128;
    int col0 = (wg % 24) * 128;
    int lane = threadIdx.x & 63, w = threadIdx.x >> 6;
    int wr = w >> 1, wc = w & 1;
    int lrow = lane & 15, lks = lane >> 4;

    GEMM_NOLDS_BODY

    int trow = row0 + wr * 64 + lks * 4;
    int tcol = col0 + wc * 64 + lrow;
#pragma unroll
    for (int m = 0; m < 4; ++m)
#pragma unroll
        for (int n = 0; n < 4; ++n) {
            int cg = tcol + n * 16;
            float bi = bias[cg];
#pragma unroll
            for (int j = 0; j < 4; ++j) {
                int rg = trow + m * 16 + j;
                float val = acc[m][n][j] + bi;
                int b = rg >> 11, tt = rg & 2047;
                if (cg < 1024) {
                    int h = cg >> 6, d = cg & 63;
                    size_t base = (size_t)(b * 16 + h) * 131072;
                    size_t idx = base + (size_t)((((tt >> 5) * 4 + (d >> 4)) * 64 + ((d >> 3) & 1) * 32 + (tt & 31)) * 8 + (d & 7));
                    qo[idx] = (bf16)(val * SCALE_Q);
                } else if (cg < 2048) {
                    int c2 = cg - 1024;
                    int h = c2 >> 6, d = c2 & 63;
                    size_t base = (size_t)(b * 16 + h) * 131072;
                    size_t idx = base + (size_t)((((tt >> 5) * 4 + (d >> 4)) * 64 + ((d >> 3) & 1) * 32 + (tt & 31)) * 8 + (d & 7));
                    ko[idx] = (bf16)val;
                } else {
                    int c2 = cg - 2048;
                    int h = c2 >> 6, d = c2 & 63;
                    size_t base = (size_t)(b * 16 + h) * 131072;
                    size_t idx = base + (size_t)(((((tt >> 6) * 4 + ((tt >> 4) & 3)) * 2 + (d >> 5)) * 64 + ((tt >> 3) & 1) * 32 + (d & 31)) * 8 + (tt & 7));
                    vo[idx] = (bf16)val;
                }
            }
        }
}

// ---------------- proj GEMM: packed A (from attn) x packed Wp -> f32 out ----------------
__global__ __launch_bounds__(256, 2) void k_gemm_proj(
    const bf16* __restrict__ Apk, const bf16* __restrict__ Bpk,
    const float* __restrict__ bias, float* __restrict__ out) {
    // XCD-chunked swizzle (bijective: 512 = 8 * 64)
    int orig = blockIdx.x;
    int wg = (orig & 7) * 64 + (orig >> 3);
    int row0 = (wg >> 3) * 128;
    int col0 = (wg & 7) * 128;
    int lane = threadIdx.x & 63, w = threadIdx.x >> 6;
    int wr = w >> 1, wc = w & 1;
    int lrow = lane & 15, lks = lane >> 4;

    GEMM_NOLDS_BODY

    int trow = row0 + wr * 64 + lks * 4;
    int tcol = col0 + wc * 64 + lrow;
#pragma unroll
    for (int m = 0; m < 4; ++m)
#pragma unroll
        for (int n = 0; n < 4; ++n) {
            int cg = tcol + n * 16;
            float bi = bias[cg];
#pragma unroll
            for (int j = 0; j < 4; ++j) {
                int rg = trow + m * 16 + j;
                out[(size_t)rg * 1024 + cg] = acc[m][n][j] + bi;
            }
        }
}

// ---------------- flash attention (causal), LDS-shared K/V, XCD head-grouping ----------------
// r12 structure; epilogue now writes y in packed-A layout for the proj GEMM.
__global__ __launch_bounds__(256, 2) void k_attn(
    const bf16* __restrict__ qp, const bf16* __restrict__ kp,
    const bf16* __restrict__ vp, bf16* __restrict__ ypk) {
    __shared__ __align__(16) bf16 Ks[2][4096];
    __shared__ __align__(16) bf16 Vs[2][4096];
    int id = blockIdx.x;
    int bxp = (id >> 3) & 7;
    int bh = (id & 7) + 8 * (id >> 6);
    int b = bh >> 4;
    int lane = threadIdx.x & 63, w = threadIdx.x >> 6;
    int tl = lane & 31, hi = lane >> 5;
    int lane8 = lane * 8;
    const bf16* Qb = qp + (size_t)bh * 131072;
    const bf16* Kb = kp + (size_t)bh * 131072;
    const bf16* Vb = vp + (size_t)bh * 131072;

    for (int qpass = 0; qpass < 2; ++qpass) {
        int qt0 = (qpass ? 15 - bxp : bxp) * 128;
        int trow0 = qt0 + w * 32;
        int t_g = trow0 + tl;

        bf16x8 qf[4];
        int qs = (trow0 >> 5) * 4;
#pragma unroll
        for (int kc = 0; kc < 4; ++kc)
            qf[kc] = *(const bf16x8*)&Qb[(qs + kc) * 512 + lane8];

        f32x16 o[2] = {};
        float m = -1e30f, l = 0.f;
        int ntb = (qt0 >> 6) + 2;
        int cur = 0;

#pragma unroll
        for (int i = 0; i < 2; ++i) {
            int u = 2 * w + i;
            async_load16(Kb + (size_t)u * 512 + lane8, &Ks[0][u * 512]);
            async_load16(Vb + (size_t)u * 512 + lane8, &Vs[0][u * 512]);
        }
        __syncthreads();

        for (int ti = 0; ti < ntb; ++ti) {
            int s0 = ti * 64;
            if (ti + 1 < ntb) {
#pragma unroll
                for (int i = 0; i < 2; ++i) {
                    int u = 2 * w + i;
                    async_load16(Kb + (size_t)((ti + 1) * 8 + u) * 512 + lane8, &Ks[cur ^ 1][u * 512]);
                    async_load16(Vb + (size_t)((ti + 1) * 8 + u) * 512 + lane8, &Vs[cur ^ 1][u * 512]);
                }
            }
            if (s0 < trow0 + 32) {
                f32x16 accs[2] = {};
                __builtin_amdgcn_s_setprio(1);
#pragma unroll
                for (int st = 0; st < 2; ++st)
#pragma unroll
                    for (int kc = 0; kc < 4; ++kc) {
                        bf16x8 kf = *(const bf16x8*)&Ks[cur][(st * 4 + kc) * 512 + lane8];
                        accs[st] = MFMA32(kf, qf[kc], accs[st]);
                    }
                __builtin_amdgcn_s_setprio(0);

                if (s0 + 63 > trow0) {
#pragma unroll
                    for (int st = 0; st < 2; ++st)
#pragma unroll
                        for (int r = 0; r < 16; ++r) {
                            int s = s0 + st * 32 + (r & 3) + 8 * (r >> 2) + 4 * hi;
                            if (s > t_g) accs[st][r] = -1e30f;
                        }
                }
                float pmax = -1e30f;
#pragma unroll
                for (int st = 0; st < 2; ++st)
#pragma unroll
                    for (int r = 0; r < 16; ++r)
                        pmax = fmaxf(pmax, accs[st][r]);
                pmax = fmaxf(pmax, __shfl_xor(pmax, 32));
                if (!__all(pmax <= m + 8.0f)) {
                    float mn = fmaxf(m, pmax);
                    float corr = __builtin_amdgcn_exp2f(m - mn);
                    m = mn;
                    l *= corr;
#pragma unroll
                    for (int dt = 0; dt < 2; ++dt)
#pragma unroll
                        for (int r = 0; r < 16; ++r)
                            o[dt][r] *= corr;
                }
                float ls = 0.f;
#pragma unroll
                for (int st = 0; st < 2; ++st)
#pragma unroll
                    for (int r = 0; r < 16; ++r) {
                        float p = __builtin_amdgcn_exp2f(accs[st][r] - m);
                        accs[st][r] = p;
                        ls += p;
                    }
                ls += __shfl_xor(ls, 32);
                l += ls;

                unsigned int pk[16];
#pragma unroll
                for (int st = 0; st < 2; ++st)
#pragma unroll
                    for (int q = 0; q < 8; ++q)
                        pk[st * 8 + q] = pack2bf(accs[st][2 * q], accs[st][2 * q + 1]);
                unsigned int rv[8];
#pragma unroll
                for (int st = 0; st < 2; ++st)
#pragma unroll
                    for (int i = 0; i < 4; ++i) {
                        int base = st * 8 + (i < 2 ? i : i + 2);
                        unsigned int send = hi ? pk[base] : pk[base + 2];
                        rv[st * 4 + i] = __shfl_xor(send, 32);
                    }
                __builtin_amdgcn_s_setprio(1);
#pragma unroll
                for (int c = 0; c < 4; ++c) {
                    const int st = c >> 1, c2 = c & 1;
                    uint32x4 pw;
                    pw.x = hi ? rv[st * 4 + 2 * c2]     : pk[st * 8 + 4 * c2];
                    pw.y = hi ? rv[st * 4 + 2 * c2 + 1] : pk[st * 8 + 4 * c2 + 1];
                    pw.z = hi ? pk[st * 8 + 4 * c2 + 2] : rv[st * 4 + 2 * c2];
                    pw.w = hi ? pk[st * 8 + 4 * c2 + 3] : rv[st * 4 + 2 * c2 + 1];
                    bf16x8 pf = __builtin_bit_cast(bf16x8, pw);
#pragma unroll
                    for (int dt = 0; dt < 2; ++dt) {
                        bf16x8 vf = *(const bf16x8*)&Vs[cur][(c * 2 + dt) * 512 + lane8];
                        o[dt] = MFMA32(vf, pf, o[dt]);
                    }
                }
                __builtin_amdgcn_s_setprio(0);
            }
            __syncthreads();
            cur ^= 1;
        }

        // epilogue: write y in packed-A layout (global row grow = b*2048 + t_g)
        int grow = b * 2048 + t_g;
        int slab = grow >> 4;
        int hkc = (bh & 15) * 2;          // y-col block hcol>>5
        float inv = 1.0f / l;
#pragma unroll
        for (int dt = 0; dt < 2; ++dt)
#pragma unroll
            for (int rq = 0; rq < 4; ++rq) {
                bf16x4v ov;
#pragma unroll
                for (int ri = 0; ri < 4; ++ri)
                    ov[ri] = (bf16)(o[dt][rq * 4 + ri] * inv);
                size_t idx = (size_t)(slab * 32 + hkc + dt) * 512 + rq * 128 + (grow & 15) * 8 + 4 * hi;
                *(bf16x4v*)&ypk[idx] = ov;
            }
    }
}

extern "C" void kernel_launch(void* const* d_in, const int* in_sizes, int n_in,
                              void* d_out, int out_size, void* d_ws, size_t ws_size,
                              hipStream_t stream) {
    const float* x = (const float*)d_in[0];
    const float* W_attn = (const float*)d_in[1];
    const float* b_attn = (const float*)d_in[2];
    const float* W_proj = (const float*)d_in[3];
    const float* b_proj = (const float*)d_in[4];
    float* out = (float*)d_out;
    float* out_mem = out + (size_t)8388608;

    char* ws = (char*)d_ws;
    bf16* xpk  = (bf16*)(ws);                        // 16MB  packed A [8192 x 1024]
    bf16* Wapk = (bf16*)(ws + ((size_t)16 << 20));   // 6MB   packed B [3072 x 1024]
    bf16* Wppk = (bf16*)(ws + ((size_t)22 << 20));   // 2MB   packed B [1024 x 1024]
    bf16* q    = (bf16*)(ws + ((size_t)24 << 20));   // 16MB  attn-packed frags
    bf16* k    = (bf16*)(ws + ((size_t)40 << 20));   // 16MB  attn-packed frags
    bf16* vT   = (bf16*)(ws + ((size_t)56 << 20));   // 16MB  attn-packed frags
    bf16* ypk  = (bf16*)(ws + ((size_t)72 << 20));   // 16MB  packed A [8192 x 1024]

    k_pre<<<6144, 256, 0, stream>>>(x, W_attn, W_proj, xpk, out_mem, Wapk, Wppk);
    k_gemm_qkv<<<1536, 256, 0, stream>>>(xpk, Wapk, b_attn, q, k, vT);
    k_attn<<<512, 256, 0, stream>>>(q, k, vT, ypk);
    k_gemm_proj<<<512, 256, 0, stream>>>(ypk, Wppk, b_proj, out);
}

// Round 14
// 178.949 us; speedup vs baseline: 1.1241x; 1.0052x over previous
//
#include <hip/hip_runtime.h>
#include <hip/hip_bf16.h>

typedef __bf16 bf16;
typedef __bf16 bf16x8 __attribute__((ext_vector_type(8)));
typedef __bf16 bf16x4v __attribute__((ext_vector_type(4)));
typedef float f32x4 __attribute__((ext_vector_type(4)));
typedef float f32x16 __attribute__((ext_vector_type(16)));
typedef float float4v __attribute__((ext_vector_type(4)));
typedef unsigned int uint32x4 __attribute__((ext_vector_type(4)));

#define MFMA16(a, b, c) __builtin_amdgcn_mfma_f32_16x16x32_bf16(a, b, c, 0, 0, 0)
#define MFMA32(a, b, c) __builtin_amdgcn_mfma_f32_32x32x16_bf16(a, b, c, 0, 0, 0)

// q pre-scale: 1/sqrt(64) * log2(e)  (softmax runs in exp2 domain)
#define SCALE_Q 0.1803368801111f

__device__ __forceinline__ void async_load16(const bf16* g, bf16* l) {
    __builtin_amdgcn_global_load_lds(
        (const __attribute__((address_space(1))) void*)g,
        (__attribute__((address_space(3))) void*)l,
        16, 0, 0);
}

__device__ __forceinline__ unsigned int pack2bf(float a, float b) {
    bf16 x = (bf16)a, y = (bf16)b;
    unsigned short ux = __builtin_bit_cast(unsigned short, x);
    unsigned short uy = __builtin_bit_cast(unsigned short, y);
    return (unsigned int)ux | ((unsigned int)uy << 16);
}

// =================== fragment-packed layout ===================
// Element (row t, k) of a [T][K] bf16 matrix lives at:
//   line = (t>>4)*(K/32) + (k>>5);  lane = (t&15) + 16*((k>>3)&3);  j = k&7
//   idx  = line*512 + lane*8 + j
// One MFMA A/B fragment (16 rows x 32 k) = one 1KB line = base + lane*16B.

// ---------------- fused preprocessing: pack x / W_attn^T / W_proj^T (+ new_memory) ----------------
__global__ void k_pre(const float* __restrict__ x, const float* __restrict__ W_attn,
                      const float* __restrict__ W_proj,
                      bf16* __restrict__ xpk, float* __restrict__ out_mem,
                      bf16* __restrict__ Wapk, bf16* __restrict__ Wppk) {
    int bid = blockIdx.x, tid = threadIdx.x;
    int lane = tid & 63;
    if (bid < 4096) {
        // x [8192][1024] -> packed A (16384 lines); fused new_memory copy
        int line = bid * 4 + (tid >> 6);
        int slab = line >> 5, kc = line & 31;
        int t = slab * 16 + (lane & 15);
        int k = kc * 32 + (lane >> 4) * 8;
        const float* src = x + (size_t)t * 1024 + k;
        float4v v0 = *(const float4v*)src;
        float4v v1 = *(const float4v*)(src + 4);
        bf16x8 o;
        o[0] = (bf16)v0.x; o[1] = (bf16)v0.y; o[2] = (bf16)v0.z; o[3] = (bf16)v0.w;
        o[4] = (bf16)v1.x; o[5] = (bf16)v1.y; o[6] = (bf16)v1.z; o[7] = (bf16)v1.w;
        *(bf16x8*)(xpk + (size_t)line * 512 + lane * 8) = o;
        int tb = t & 2047;
        if (tb >= 1536) {
            float* dst = out_mem + ((size_t)(t >> 11) * 512 + (tb - 1536)) * 1024 + k;
            *(float4v*)dst = v0;
            *(float4v*)(dst + 4) = v1;
        }
    } else if (bid < 4096 + 1536) {
        // W_attn [1024][3072] -> packed B^T (cols n as rows): 6144 lines
        int line = (bid - 4096) * 4 + (tid >> 6);
        int slab = line >> 5, kc = line & 31;
        int n = slab * 16 + (lane & 15);
        int k = kc * 32 + (lane >> 4) * 8;
        bf16x8 o;
#pragma unroll
        for (int j = 0; j < 8; ++j)
            o[j] = (bf16)W_attn[(size_t)(k + j) * 3072 + n];
        *(bf16x8*)(Wapk + (size_t)line * 512 + lane * 8) = o;
    } else {
        // W_proj [1024][1024] -> packed B^T: 2048 lines
        int line = (bid - 5632) * 4 + (tid >> 6);
        int slab = line >> 5, kc = line & 31;
        int n = slab * 16 + (lane & 15);
        int k = kc * 32 + (lane >> 4) * 8;
        bf16x8 o;
#pragma unroll
        for (int j = 0; j < 8; ++j)
            o[j] = (bf16)W_proj[(size_t)(k + j) * 1024 + n];
        *(bf16x8*)(Wppk + (size_t)line * 512 + lane * 8) = o;
    }
}

// =================== LDS-free, barrier-free 128x128 GEMM body (r13) ===================
#define GEMM_NOLDS_BODY                                                                  \
    const bf16* Ab[4]; const bf16* Bb[4];                                                \
    _Pragma("unroll")                                                                    \
    for (int m = 0; m < 4; ++m)                                                          \
        Ab[m] = Apk + (size_t)(((row0 >> 4) + wr * 4 + m) * 32) * 512 + lane * 8;        \
    _Pragma("unroll")                                                                    \
    for (int n = 0; n < 4; ++n)                                                          \
        Bb[n] = Bpk + (size_t)(((col0 >> 4) + wc * 4 + n) * 32) * 512 + lane * 8;        \
    f32x4 acc[4][4] = {};                                                                \
    bf16x8 a0[4], b0[4], a1[4], b1[4];                                                   \
    _Pragma("unroll")                                                                    \
    for (int m = 0; m < 4; ++m) a0[m] = *(const bf16x8*)(Ab[m]);                         \
    _Pragma("unroll")                                                                    \
    for (int n = 0; n < 4; ++n) b0[n] = *(const bf16x8*)(Bb[n]);                         \
    for (int t = 0; t < 16; ++t) {                                                       \
        int o1 = (2 * t + 1) * 512;                                                      \
        _Pragma("unroll")                                                                \
        for (int m = 0; m < 4; ++m) a1[m] = *(const bf16x8*)(Ab[m] + o1);                \
        _Pragma("unroll")                                                                \
        for (int n = 0; n < 4; ++n) b1[n] = *(const bf16x8*)(Bb[n] + o1);                \
        __builtin_amdgcn_s_setprio(1);                                                   \
        _Pragma("unroll")                                                                \
        for (int m = 0; m < 4; ++m)                                                      \
            _Pragma("unroll")                                                            \
            for (int n = 0; n < 4; ++n)                                                  \
                acc[m][n] = MFMA16(a0[m], b0[n], acc[m][n]);                             \
        __builtin_amdgcn_s_setprio(0);                                                   \
        if (t < 15) {                                                                    \
            int o2 = (2 * t + 2) * 512;                                                  \
            _Pragma("unroll")                                                            \
            for (int m = 0; m < 4; ++m) a0[m] = *(const bf16x8*)(Ab[m] + o2);            \
            _Pragma("unroll")                                                            \
            for (int n = 0; n < 4; ++n) b0[n] = *(const bf16x8*)(Bb[n] + o2);            \
        }                                                                                \
        __builtin_amdgcn_s_setprio(1);                                                   \
        _Pragma("unroll")                                                                \
        for (int m = 0; m < 4; ++m)                                                      \
            _Pragma("unroll")                                                            \
            for (int n = 0; n < 4; ++n)                                                  \
                acc[m][n] = MFMA16(a1[m], b1[n], acc[m][n]);                             \
        __builtin_amdgcn_s_setprio(0);                                                   \
    }

// ---------------- QKV GEMM with fragment-packed scatter epilogue ----------------
__global__ __launch_bounds__(256, 2) void k_gemm_qkv(
    const bf16* __restrict__ Apk, const bf16* __restrict__ Bpk,
    const float* __restrict__ bias,
    bf16* __restrict__ qo, bf16* __restrict__ ko, bf16* __restrict__ vo) {
    // XCD-chunked swizzle (bijective: 1536 = 8 * 192)
    int orig = blockIdx.x;
    int wg = (orig & 7) * 192 + (orig >> 3);
    int row0 = (wg / 24) * 128;
    int col0 = (wg % 24) * 128;
    int lane = threadIdx.x & 63, w = threadIdx.x >> 6;
    int wr = w >> 1, wc = w & 1;
    int lrow = lane & 15, lks = lane >> 4;

    GEMM_NOLDS_BODY

    int trow = row0 + wr * 64 + lks * 4;
    int tcol = col0 + wc * 64 + lrow;
#pragma unroll
    for (int m = 0; m < 4; ++m)
#pragma unroll
        for (int n = 0; n < 4; ++n) {
            int cg = tcol + n * 16;
            float bi = bias[cg];
#pragma unroll
            for (int j = 0; j < 4; ++j) {
                int rg = trow + m * 16 + j;
                float val = acc[m][n][j] + bi;
                int b = rg >> 11, tt = rg & 2047;
                if (cg < 1024) {
                    int h = cg >> 6, d = cg & 63;
                    size_t base = (size_t)(b * 16 + h) * 131072;
                    size_t idx = base + (size_t)((((tt >> 5) * 4 + (d >> 4)) * 64 + ((d >> 3) & 1) * 32 + (tt & 31)) * 8 + (d & 7));
                    qo[idx] = (bf16)(val * SCALE_Q);
                } else if (cg < 2048) {
                    int c2 = cg - 1024;
                    int h = c2 >> 6, d = c2 & 63;
                    size_t base = (size_t)(b * 16 + h) * 131072;
                    size_t idx = base + (size_t)((((tt >> 5) * 4 + (d >> 4)) * 64 + ((d >> 3) & 1) * 32 + (tt & 31)) * 8 + (d & 7));
                    ko[idx] = (bf16)val;
                } else {
                    int c2 = cg - 2048;
                    int h = c2 >> 6, d = c2 & 63;
                    size_t base = (size_t)(b * 16 + h) * 131072;
                    size_t idx = base + (size_t)(((((tt >> 6) * 4 + ((tt >> 4) & 3)) * 2 + (d >> 5)) * 64 + ((tt >> 3) & 1) * 32 + (d & 31)) * 8 + (tt & 7));
                    vo[idx] = (bf16)val;
                }
            }
        }
}

// ---------------- proj GEMM: packed A (from attn) x packed Wp -> f32 out ----------------
__global__ __launch_bounds__(256, 2) void k_gemm_proj(
    const bf16* __restrict__ Apk, const bf16* __restrict__ Bpk,
    const float* __restrict__ bias, float* __restrict__ out) {
    // XCD-chunked swizzle (bijective: 512 = 8 * 64)
    int orig = blockIdx.x;
    int wg = (orig & 7) * 64 + (orig >> 3);
    int row0 = (wg >> 3) * 128;
    int col0 = (wg & 7) * 128;
    int lane = threadIdx.x & 63, w = threadIdx.x >> 6;
    int wr = w >> 1, wc = w & 1;
    int lrow = lane & 15, lks = lane >> 4;

    GEMM_NOLDS_BODY

    int trow = row0 + wr * 64 + lks * 4;
    int tcol = col0 + wc * 64 + lrow;
#pragma unroll
    for (int m = 0; m < 4; ++m)
#pragma unroll
        for (int n = 0; n < 4; ++n) {
            int cg = tcol + n * 16;
            float bi = bias[cg];
#pragma unroll
            for (int j = 0; j < 4; ++j) {
                int rg = trow + m * 16 + j;
                out[(size_t)rg * 1024 + cg] = acc[m][n][j] + bi;
            }
        }
}

// ---------------- flash attention (causal): counted-vmcnt barrier discipline ----------------
// r13 structure; __syncthreads (vmcnt(0)-draining) replaced with the r9/r11-proven
// {stage -> vmcnt(4) -> barrier -> compute -> lgkmcnt(0) -> barrier} pattern so
// prefetch loads ride across the barrier pair. Per-wave load counts uniform
// (each wave stages its own 2 K + 2 V chunks).
__global__ __launch_bounds__(256, 2) void k_attn(
    const bf16* __restrict__ qp, const bf16* __restrict__ kp,
    const bf16* __restrict__ vp, bf16* __restrict__ ypk) {
    __shared__ __align__(16) bf16 Ks[2][4096];
    __shared__ __align__(16) bf16 Vs[2][4096];
    int id = blockIdx.x;
    int bxp = (id >> 3) & 7;
    int bh = (id & 7) + 8 * (id >> 6);
    int b = bh >> 4;
    int lane = threadIdx.x & 63, w = threadIdx.x >> 6;
    int tl = lane & 31, hi = lane >> 5;
    int lane8 = lane * 8;
    const bf16* Qb = qp + (size_t)bh * 131072;
    const bf16* Kb = kp + (size_t)bh * 131072;
    const bf16* Vb = vp + (size_t)bh * 131072;

    for (int qpass = 0; qpass < 2; ++qpass) {
        int qt0 = (qpass ? 15 - bxp : bxp) * 128;
        int trow0 = qt0 + w * 32;
        int t_g = trow0 + tl;

        bf16x8 qf[4];
        int qs = (trow0 >> 5) * 4;
#pragma unroll
        for (int kc = 0; kc < 4; ++kc)
            qf[kc] = *(const bf16x8*)&Qb[(qs + kc) * 512 + lane8];

        f32x16 o[2] = {};
        float m = -1e30f, l = 0.f;
        int ntb = (qt0 >> 6) + 2;
        int cur = 0;

        // prologue: stage tile 0 into buf 0 (4 loads per wave)
#pragma unroll
        for (int i = 0; i < 2; ++i) {
            int u = 2 * w + i;
            async_load16(Kb + (size_t)u * 512 + lane8, &Ks[0][u * 512]);
            async_load16(Vb + (size_t)u * 512 + lane8, &Vs[0][u * 512]);
        }

        for (int ti = 0; ti < ntb; ++ti) {
            int s0 = ti * 64;
            if (ti + 1 < ntb) {
#pragma unroll
                for (int i = 0; i < 2; ++i) {
                    int u = 2 * w + i;
                    async_load16(Kb + (size_t)((ti + 1) * 8 + u) * 512 + lane8, &Ks[cur ^ 1][u * 512]);
                    async_load16(Vb + (size_t)((ti + 1) * 8 + u) * 512 + lane8, &Vs[cur ^ 1][u * 512]);
                }
                asm volatile("s_waitcnt vmcnt(4)" ::: "memory");   // tile ti landed (mine)
            } else {
                asm volatile("s_waitcnt vmcnt(0)" ::: "memory");
            }
            __builtin_amdgcn_sched_barrier(0);
            __builtin_amdgcn_s_barrier();      // B1: tile ti landed for ALL waves
            __builtin_amdgcn_sched_barrier(0);

            if (s0 < trow0 + 32) {
                f32x16 accs[2] = {};
                __builtin_amdgcn_s_setprio(1);
#pragma unroll
                for (int st = 0; st < 2; ++st)
#pragma unroll
                    for (int kc = 0; kc < 4; ++kc) {
                        bf16x8 kf = *(const bf16x8*)&Ks[cur][(st * 4 + kc) * 512 + lane8];
                        accs[st] = MFMA32(kf, qf[kc], accs[st]);
                    }
                __builtin_amdgcn_s_setprio(0);

                if (s0 + 63 > trow0) {
#pragma unroll
                    for (int st = 0; st < 2; ++st)
#pragma unroll
                        for (int r = 0; r < 16; ++r) {
                            int s = s0 + st * 32 + (r & 3) + 8 * (r >> 2) + 4 * hi;
                            if (s > t_g) accs[st][r] = -1e30f;
                        }
                }
                float pmax = -1e30f;
#pragma unroll
                for (int st = 0; st < 2; ++st)
#pragma unroll
                    for (int r = 0; r < 16; ++r)
                        pmax = fmaxf(pmax, accs[st][r]);
                pmax = fmaxf(pmax, __shfl_xor(pmax, 32));
                if (!__all(pmax <= m + 8.0f)) {
                    float mn = fmaxf(m, pmax);
                    float corr = __builtin_amdgcn_exp2f(m - mn);
                    m = mn;
                    l *= corr;
#pragma unroll
                    for (int dt = 0; dt < 2; ++dt)
#pragma unroll
                        for (int r = 0; r < 16; ++r)
                            o[dt][r] *= corr;
                }
                float ls = 0.f;
#pragma unroll
                for (int st = 0; st < 2; ++st)
#pragma unroll
                    for (int r = 0; r < 16; ++r) {
                        float p = __builtin_amdgcn_exp2f(accs[st][r] - m);
                        accs[st][r] = p;
                        ls += p;
                    }
                ls += __shfl_xor(ls, 32);
                l += ls;

                unsigned int pk[16];
#pragma unroll
                for (int st = 0; st < 2; ++st)
#pragma unroll
                    for (int q = 0; q < 8; ++q)
                        pk[st * 8 + q] = pack2bf(accs[st][2 * q], accs[st][2 * q + 1]);
                unsigned int rv[8];
#pragma unroll
                for (int st = 0; st < 2; ++st)
#pragma unroll
                    for (int i = 0; i < 4; ++i) {
                        int base = st * 8 + (i < 2 ? i : i + 2);
                        unsigned int send = hi ? pk[base] : pk[base + 2];
                        rv[st * 4 + i] = __shfl_xor(send, 32);
                    }
                __builtin_amdgcn_s_setprio(1);
#pragma unroll
                for (int c = 0; c < 4; ++c) {
                    const int st = c >> 1, c2 = c & 1;
                    uint32x4 pw;
                    pw.x = hi ? rv[st * 4 + 2 * c2]     : pk[st * 8 + 4 * c2];
                    pw.y = hi ? rv[st * 4 + 2 * c2 + 1] : pk[st * 8 + 4 * c2 + 1];
                    pw.z = hi ? pk[st * 8 + 4 * c2 + 2] : rv[st * 4 + 2 * c2];
                    pw.w = hi ? pk[st * 8 + 4 * c2 + 3] : rv[st * 4 + 2 * c2 + 1];
                    bf16x8 pf = __builtin_bit_cast(bf16x8, pw);
#pragma unroll
                    for (int dt = 0; dt < 2; ++dt) {
                        bf16x8 vf = *(const bf16x8*)&Vs[cur][(c * 2 + dt) * 512 + lane8];
                        o[dt] = MFMA32(vf, pf, o[dt]);
                    }
                }
                __builtin_amdgcn_s_setprio(0);
            }
            asm volatile("s_waitcnt lgkmcnt(0)" ::: "memory");
            __builtin_amdgcn_sched_barrier(0);
            __builtin_amdgcn_s_barrier();      // B2: all waves done reading buf cur
            __builtin_amdgcn_sched_barrier(0);
            cur ^= 1;
        }

        // epilogue: write y in packed-A layout (global row grow = b*2048 + t_g)
        int grow = b * 2048 + t_g;
        int slab = grow >> 4;
        int hkc = (bh & 15) * 2;          // y-col block hcol>>5
        float inv = 1.0f / l;
#pragma unroll
        for (int dt = 0; dt < 2; ++dt)
#pragma unroll
            for (int rq = 0; rq < 4; ++rq) {
                bf16x4v ov;
#pragma unroll
                for (int ri = 0; ri < 4; ++ri)
                    ov[ri] = (bf16)(o[dt][rq * 4 + ri] * inv);
                size_t idx = (size_t)(slab * 32 + hkc + dt) * 512 + rq * 128 + (grow & 15) * 8 + 4 * hi;
                *(bf16x4v*)&ypk[idx] = ov;
            }
    }
}

extern "C" void kernel_launch(void* const* d_in, const int* in_sizes, int n_in,
                              void* d_out, int out_size, void* d_ws, size_t ws_size,
                              hipStream_t stream) {
    const float* x = (const float*)d_in[0];
    const float* W_attn = (const float*)d_in[1];
    const float* b_attn = (const float*)d_in[2];
    const float* W_proj = (const float*)d_in[3];
    const float* b_proj = (const float*)d_in[4];
    float* out = (float*)d_out;
    float* out_mem = out + (size_t)8388608;

    char* ws = (char*)d_ws;
    bf16* xpk  = (bf16*)(ws);                        // 16MB  packed A [8192 x 1024]
    bf16* Wapk = (bf16*)(ws + ((size_t)16 << 20));   // 6MB   packed B [3072 x 1024]
    bf16* Wppk = (bf16*)(ws + ((size_t)22 << 20));   // 2MB   packed B [1024 x 1024]
    bf16* q    = (bf16*)(ws + ((size_t)24 << 20));   // 16MB  attn-packed frags
    bf16* k    = (bf16*)(ws + ((size_t)40 << 20));   // 16MB  attn-packed frags
    bf16* vT   = (bf16*)(ws + ((size_t)56 << 20));   // 16MB  attn-packed frags
    bf16* ypk  = (bf16*)(ws + ((size_t)72 << 20));   // 16MB  packed A [8192 x 1024]

    k_pre<<<6144, 256, 0, stream>>>(x, W_attn, W_proj, xpk, out_mem, Wapk, Wppk);
    k_gemm_qkv<<<1536, 256, 0, stream>>>(xpk, Wapk, b_attn, q, k, vT);
    k_attn<<<512, 256, 0, stream>>>(q, k, vT, ypk);
    k_gemm_proj<<<512, 256, 0, stream>>>(ypk, Wppk, b_proj, out);
}